// Round 1
// 538.331 us; speedup vs baseline: 1.1185x; 1.1185x over previous
//
#include <hip/hip_runtime.h>
#include <math.h>

// x: [1,32,32,32,80] fp32 (80 = 32 scalars + 16 vec*3)
// conv: low-rank kernel basis 12 = 3 radial * {1, Yd, Yh, Yw}
//   stage A (tap-pair): z[v][j*80+ci] fp32
//   stage B (NEW): y = z @ W via split-bf16 MFMA (3-term emulation), gate -> fp32 [v][80]
// out: [1,64,64,64,80] fp32

typedef __attribute__((ext_vector_type(8))) short bf16x8;
typedef __attribute__((ext_vector_type(4))) float f32x4;

__device__ __forceinline__ int eps3(int a, int m, int b) {
    if (a == b || a == m || m == b) return 0;
    return ((a==0&&m==1&&b==2)||(a==1&&m==2&&b==0)||(a==2&&m==0&&b==1)) ? 1 : -1;
}

// ---------------------------------------------------------------- tap-pair table
__global__ void build_tap(float* __restrict__ tap) {
    int t = threadIdx.x;
    if (t >= 125) return;
    int td = t / 25 - 2, th = (t / 5) % 5 - 2, tw = t % 5 - 2;
    int n2 = td*td + th*th + tw*tw;
    if (t == 62) {                       // center tap
        float* rec = tap + 40 * 16;
        rec[0] = __int_as_float(0); rec[1] = __int_as_float(0);
        for (int r = 0; r < 3; r++) {
            float tt = (0.f - 1.25f * (float)r) * 0.8f;
            rec[4 + r] = expf(-tt * tt);
        }
        return;
    }
    bool active = n2 <= 6;
    bool pos = (td > 0) || (td == 0 && th > 0) || (td == 0 && th == 0 && tw > 0);
    if (!(active && pos)) return;
    int idx = 0;                          // compact index among positive reps
    for (int q = 0; q < t; q++) {
        int qd = q / 25 - 2, qh = (q / 5) % 5 - 2, qw = q % 5 - 2;
        int m2 = qd*qd + qh*qh + qw*qw;
        bool p = (qd > 0) || (qd == 0 && qh > 0) || (qd == 0 && qh == 0 && qw > 0);
        if (m2 <= 6 && p) idx++;
    }
    float* rec = tap + idx * 16;
    rec[0] = __int_as_float((td+2)*120 + (th+2)*20 + (tw+2) - (2*120 + 2*20 + 2));
    rec[1] = __int_as_float((2-td)*120 + (2-th)*20 + (2-tw) - (2*120 + 2*20 + 2));
    float norm = sqrtf((float)n2);
    float comp[3] = {(float)td, (float)th, (float)tw};
    for (int r = 0; r < 3; r++) {
        float tt = (norm - 1.25f * (float)r) * 0.8f;
        float R = expf(-tt * tt);
        rec[4 + r] = R;
        for (int m = 0; m < 3; m++)
            rec[7 + r*3 + m] = R * 1.7320508075688772f * comp[m] / norm;
    }
}

// ---------------------------------------------------------------- W matrices (fp32 source)
// W[conv][j*80+ci][co], j = r*4+alpha.  2*12*80*96 = 184320 entries.
__global__ void build_W(float* __restrict__ W,
    const float* __restrict__ ss1, const float* __restrict__ sv1,
    const float* __restrict__ vs1, const float* __restrict__ vv01, const float* __restrict__ vv11,
    const float* __restrict__ ss2, const float* __restrict__ sv2,
    const float* __restrict__ vs2, const float* __restrict__ vv02, const float* __restrict__ vv12)
{
    int idx = threadIdx.x + blockIdx.x * 256;
    if (idx >= 184320) return;
    int conv = idx / 92160;
    int rem  = idx % 92160;
    int j  = rem / 7680;
    int ci = (rem / 96) % 80;
    int co = rem % 96;
    int r = j >> 2, al = j & 3;
    const float* ss  = conv ? ss2  : ss1;
    const float* sv  = conv ? sv2  : sv1;
    const float* vs  = conv ? vs2  : vs1;
    const float* vv0 = conv ? vv02 : vv01;
    const float* vv1 = conv ? vv12 : vv11;
    float val = 0.f;
    if (ci < 32) {
        if (co < 48) { if (al == 0) val = ss[(r*32 + ci)*48 + co]; }
        else {
            int o = (co - 48) / 3, m = (co - 48) % 3;
            if (al == m + 1) val = sv[(r*32 + ci)*16 + o];
        }
    } else {
        int i = (ci - 32) / 3, a = (ci - 32) % 3;
        if (co < 48) { if (al == a + 1) val = vs[(r*16 + i)*48 + co] * 0.5773502691896258f; }
        else {
            int o = (co - 48) / 3, b = (co - 48) % 3;
            if (al == 0) { if (a == b) val = vv0[(r*16 + i)*16 + o]; }
            else {
                int e = eps3(a, al - 1, b);
                if (e) val = vv1[(r*16 + i)*16 + o] * (float)e * 0.7071067811865476f;
            }
        }
    }
    W[idx] = val;
}

// ---------------------------------------------------------------- W split to bf16 hi/lo, transposed
// Wh/Wl layout: [conv][co][k] with k = j*80+ci contiguous (960).  RNE both terms.
__global__ void build_Wt(const float* __restrict__ W,
                         unsigned short* __restrict__ Wh, unsigned short* __restrict__ Wl)
{
    int idx = threadIdx.x + blockIdx.x * 256;    // over 2*96*960
    if (idx >= 184320) return;
    int conv = idx / 92160, rem = idx % 92160;
    int co = rem / 960, k = rem % 960;
    float w = W[conv * 92160 + k * 96 + co];
    unsigned int u = __float_as_uint(w);
    unsigned int hib = (u + 0x7FFFu + ((u >> 16) & 1u)) & 0xFFFF0000u;  // RNE bf16, as f32 bits
    float res = w - __uint_as_float(hib);
    unsigned int v = __float_as_uint(res);
    unsigned int lob = (v + 0x7FFFu + ((v >> 16) & 1u)) >> 16;
    Wh[idx] = (unsigned short)(hib >> 16);
    Wl[idx] = (unsigned short)lob;
}

// ---------------------------------------------------------------- Stage A (tap-pair, fp32 out)
__global__ __launch_bounds__(256) void basis_conv3(
    const float* __restrict__ xin, float* __restrict__ z,
    const float* __restrict__ tap, int d0)
{
    __shared__ float xs[4][2880];        // 4 ci-groups x (720 float4) = 46 KB
    int tid = threadIdx.x;
    int cl = tid >> 6;                   // ci-group lane (wave-uniform)
    int vl64 = tid & 63;
    int dl = vl64 >> 5, hl = (vl64 >> 4) & 1, wl = vl64 & 15;
    int bid = blockIdx.x;
    int dt = d0 + ((bid >> 5) << 1);
    int h0 = ((bid >> 1) & 15) << 1;
    int w0 = (bid & 1) << 4;
    int vl = ((dt + dl - d0) << 10) + ((h0 + hl) << 5) + w0 + wl;  // slab-local
    float* zp = z + (size_t)vl * 960;

    for (int cb = 0; cb < 20; cb += 4) {
        __syncthreads();
        for (int i = tid; i < 2880; i += 256) {
            int sl = i / 720, rr = i - sl * 720;
            int dd = rr / 120, rm = rr - dd * 120;
            int hh = rm / 20, ww = rm - hh * 20;
            int gd = dt + dd - 2, gh = h0 + hh - 2, gw = w0 + ww - 2;
            float4 val = make_float4(0.f, 0.f, 0.f, 0.f);
            if (gd >= 0 && gd < 32 && gh >= 0 && gh < 32 && gw >= 0 && gw < 32)
                val = *reinterpret_cast<const float4*>(
                    xin + (size_t)(((gd << 5) + gh) * 32 + gw) * 80 + (cb + sl) * 4);
            *reinterpret_cast<float4*>(&xs[sl][rr * 4]) = val;
        }
        __syncthreads();
        const float* xp = &xs[cl][((dl + 2) * 120 + (hl + 2) * 20 + (wl + 2)) * 4];
        float acc[12][4];
        #pragma unroll
        for (int j = 0; j < 12; j++)
            #pragma unroll
            for (int c = 0; c < 4; c++) acc[j][c] = 0.f;
        {   // center
            const float* rec = tap + 640;
            float4 xc = *reinterpret_cast<const float4*>(xp);
            #pragma unroll
            for (int r = 0; r < 3; r++) {
                float R = rec[4 + r];
                acc[r*4][0] += R * xc.x; acc[r*4][1] += R * xc.y;
                acc[r*4][2] += R * xc.z; acc[r*4][3] += R * xc.w;
            }
        }
        for (int p = 0; p < 40; p++) {
            const float* rec = tap + p * 16;
            int op = __float_as_int(rec[0]) * 4, om = __float_as_int(rec[1]) * 4;
            float4 xa = *reinterpret_cast<const float4*>(xp + op);
            float4 xb = *reinterpret_cast<const float4*>(xp + om);
            float s[4], d[4];
            s[0] = xa.x + xb.x; s[1] = xa.y + xb.y; s[2] = xa.z + xb.z; s[3] = xa.w + xb.w;
            d[0] = xa.x - xb.x; d[1] = xa.y - xb.y; d[2] = xa.z - xb.z; d[3] = xa.w - xb.w;
            #pragma unroll
            for (int r = 0; r < 3; r++) {
                float R = rec[4 + r];
                #pragma unroll
                for (int c = 0; c < 4; c++) acc[r*4][c] += R * s[c];
                #pragma unroll
                for (int m = 0; m < 3; m++) {
                    float RY = rec[7 + r*3 + m];
                    #pragma unroll
                    for (int c = 0; c < 4; c++) acc[r*4 + m + 1][c] += RY * d[c];
                }
            }
        }
        int cig = cb + cl;
        #pragma unroll
        for (int j = 0; j < 12; j++)
            *reinterpret_cast<float4*>(zp + j * 80 + cig * 4) =
                make_float4(acc[j][0], acc[j][1], acc[j][2], acc[j][3]);
    }
}

// ---------------------------------------------------------------- Stage B (split-bf16 MFMA)
// Block: 128 voxels, 4 waves x 32 rows x 96 cols.  No LDS in K-loop.
// A (z) split in-register: hi = truncate-to-bf16, lo = bf16(residual).
// y = Ah*Bh + Al*Bh + Ah*Bl accumulated in fp32 MFMA (rel err ~2^-16).
__device__ __forceinline__ void split8(float4 a, float4 b, bf16x8& hi, bf16x8& lo) {
    float av[8] = {a.x, a.y, a.z, a.w, b.x, b.y, b.z, b.w};
    #pragma unroll
    for (int e = 0; e < 8; e++) {
        unsigned int u = __float_as_uint(av[e]);
        hi[e] = (short)(u >> 16);
        float res = av[e] - __uint_as_float(u & 0xFFFF0000u);
        lo[e] = (short)(__float_as_uint(res) >> 16);
    }
}

__global__ __launch_bounds__(256) void gemm_gate(
    const float* __restrict__ z, const unsigned short* __restrict__ Wh,
    const unsigned short* __restrict__ Wl, float* __restrict__ xout, int d0)
{
    __shared__ float y[128 * 97];        // gate buffer only (epilogue)
    int t = threadIdx.x;
    int w = t >> 6, l = t & 63;
    int lr = l & 15, lk = l >> 4;        // A/B row-in-tile, k-group (k = lk*8 + e)
    int vbase = blockIdx.x * 128;        // slab-local
    const float* za = z + (size_t)(vbase + w * 32 + lr) * 960 + lk * 8;
    const float* zb = za + 16 * 960;
    const unsigned short* bhp = Wh + lr * 960 + lk * 8;
    const unsigned short* blp = Wl + lr * 960 + lk * 8;

    const f32x4 fzero = {0.f, 0.f, 0.f, 0.f};
    f32x4 acc[2][6];
    #pragma unroll
    for (int m = 0; m < 2; m++)
        #pragma unroll
        for (int nt = 0; nt < 6; nt++) acc[m][nt] = fzero;

    for (int kc = 0; kc < 960; kc += 32) {
        bf16x8 ah0, al0, ah1, al1;
        split8(*reinterpret_cast<const float4*>(za + kc),
               *reinterpret_cast<const float4*>(za + kc + 4), ah0, al0);
        split8(*reinterpret_cast<const float4*>(zb + kc),
               *reinterpret_cast<const float4*>(zb + kc + 4), ah1, al1);
        #pragma unroll
        for (int nt = 0; nt < 6; nt++) {
            bf16x8 bh = *reinterpret_cast<const bf16x8*>(bhp + nt * 15360 + kc);
            bf16x8 bl = *reinterpret_cast<const bf16x8*>(blp + nt * 15360 + kc);
            acc[0][nt] = __builtin_amdgcn_mfma_f32_16x16x32_bf16(ah0, bh, acc[0][nt], 0, 0, 0);
            acc[1][nt] = __builtin_amdgcn_mfma_f32_16x16x32_bf16(ah1, bh, acc[1][nt], 0, 0, 0);
            acc[0][nt] = __builtin_amdgcn_mfma_f32_16x16x32_bf16(al0, bh, acc[0][nt], 0, 0, 0);
            acc[1][nt] = __builtin_amdgcn_mfma_f32_16x16x32_bf16(al1, bh, acc[1][nt], 0, 0, 0);
            acc[0][nt] = __builtin_amdgcn_mfma_f32_16x16x32_bf16(ah0, bl, acc[0][nt], 0, 0, 0);
            acc[1][nt] = __builtin_amdgcn_mfma_f32_16x16x32_bf16(ah1, bl, acc[1][nt], 0, 0, 0);
        }
    }
    // C/D layout (verified): col = lane&15, row = (lane>>4)*4 + reg
    #pragma unroll
    for (int m = 0; m < 2; m++)
        #pragma unroll
        for (int nt = 0; nt < 6; nt++)
            #pragma unroll
            for (int r = 0; r < 4; r++)
                y[(w * 32 + m * 16 + lk * 4 + r) * 97 + nt * 16 + lr] = acc[m][nt][r];
    __syncthreads();
    int gbase = d0 * 1024 + vbase;
    for (int idx = t; idx < 128 * 80; idx += 256) {
        int vr = idx / 80, c = idx % 80;
        const float* yr = y + vr * 97;
        float val;
        if (c < 32) val = fmaxf(yr[c], 0.f);
        else {
            int q = c - 32;
            float g = 1.f / (1.f + __expf(-yr[32 + q / 3]));
            val = yr[48 + q] * g;
        }
        xout[(size_t)(gbase + vr) * 80 + c] = val;
    }
}

// ---------------------------------------------------------------- Final head (unchanged)
__global__ __launch_bounds__(256) void final_k(
    const float* __restrict__ x2, const float* __restrict__ wls,
    const float* __restrict__ wlv, const float* __restrict__ wpos,
    float* __restrict__ out)
{
    __shared__ float xv[16 * 81];
    __shared__ float coeff[16 * 161];
    __shared__ float s_wls[512];
    __shared__ float s_wlv[768];
    int t = threadIdx.x;
    int bid = blockIdx.x;
    int cw0 = (bid & 1) * 16;
    int ch  = (bid >> 1) & 31;
    int cd  = bid >> 6;
    float wp = wpos[0];
    {
        int base = ((cd * 32 + ch) * 32 + cw0) * 80;
        #pragma unroll
        for (int i = t; i < 1280; i += 256) {
            int vi = i / 80, c = i % 80;
            xv[vi * 81 + c] = x2[base + i];
        }
        for (int i = t; i < 512; i += 256) s_wls[i] = wls[i];
        for (int i = t; i < 768; i += 256) s_wlv[i] = wlv[i];
    }
    __syncthreads();
    {
        int vi = t >> 4, j = t & 15;
        const float* xp = xv + vi * 81;
        float* cf = coeff + vi * 161;
        #pragma unroll
        for (int l = 0; l < 10; l++) {
            int q = l * 16 + j;
            float sum = 0.f;
            if (q < 96) {
                int o = q / 3, m = q % 3;
                #pragma unroll
                for (int c = 0; c < 16; c++) sum += xp[32 + c * 3 + m] * s_wls[c * 32 + o];
            } else if (q < 112) {
                int o = q - 96;
                #pragma unroll
                for (int c = 0; c < 32; c++) sum += xp[c] * s_wlv[c * 16 + o];
            } else {
                int q2 = q - 112; int o = q2 / 3, m = q2 % 3;
                #pragma unroll
                for (int c = 0; c < 16; c++) sum += xp[32 + c * 3 + m] * s_wlv[(32 + c) * 16 + o];
            }
            cf[q] = sum;
        }
    }
    __syncthreads();
    const float scale = 0.14433756729740643f;
    #pragma unroll
    for (int f01 = 0; f01 < 4; f01++) {
        int fd = 2 * cd + (f01 >> 1), fh = 2 * ch + (f01 & 1);
        float p0 = wp * (float)(cd + (f01 >> 1) - 16);
        float p1 = wp * (float)(ch + (f01 & 1) - 16);
        size_t obase = (size_t)((fd * 64 + fh) * 64 + cw0 * 2) * 80;
        #pragma unroll
        for (int it = 0; it < 10; it++) {
            int idx = it * 256 + t;
            int fwl = idx / 80, c = idx - fwl * 80;
            int vi = fwl >> 1;
            float p2 = wp * (float)(cw0 + vi + (fwl & 1) - 16);
            const float* cf = coeff + vi * 161;
            float val;
            if (c < 32) {
                val = cf[c * 3] * p0 + cf[c * 3 + 1] * p1 + cf[c * 3 + 2] * p2;
            } else {
                int q = c - 32, o = q / 3, m = q - o * 3;
                float A = cf[96 + o];
                const float* w2 = cf + 112 + o * 3;
                float pm, crm;
                if (m == 0)      { pm = p0; crm = w2[1] * p2 - w2[2] * p1; }
                else if (m == 1) { pm = p1; crm = w2[2] * p0 - w2[0] * p2; }
                else             { pm = p2; crm = w2[0] * p1 - w2[1] * p0; }
                val = A * pm + crm * 0.7071067811865476f;
            }
            out[obase + idx] = val * scale;
        }
    }
}

// ----------------------------------------------------------------
extern "C" void kernel_launch(void* const* d_in, const int* in_sizes, int n_in,
                              void* d_out, int out_size, void* d_ws, size_t ws_size,
                              hipStream_t stream)
{
    const float* x    = (const float*)d_in[0];
    const float* wpos = (const float*)d_in[11];
    const float* wls  = (const float*)d_in[12];
    const float* wlv  = (const float*)d_in[13];
    float* out = (float*)d_out;
    float* ws  = (float*)d_ws;

    float* tap = ws;                        // 656 floats -> pad 1024
    float* W   = ws + 1024;                 // 184320 fp32
    unsigned short* Wh = (unsigned short*)(ws + 1024 + 184320);   // 184320 ushorts
    unsigned short* Wl = Wh + 184320;                              // 184320 ushorts
    float* x1  = ws + 1024 + 184320 + 184320;   // (2 ushort arrays = 184320 floats)
    float* x2  = x1 + 2621440;
    float* z   = x2 + 2621440;
    size_t fixedf = 1024 + 184320 + 184320 + 2ull * 2621440;
    size_t wsf = ws_size / 4;
    int slabD = 32;                          // shrink z slab if ws is small
    while (slabD > 2 && fixedf + (size_t)1024 * slabD * 960 > wsf) slabD >>= 1;

    build_tap<<<1, 128, 0, stream>>>(tap);
    build_W<<<720, 256, 0, stream>>>(W,
        (const float*)d_in[1], (const float*)d_in[2], (const float*)d_in[3],
        (const float*)d_in[4], (const float*)d_in[5],
        (const float*)d_in[6], (const float*)d_in[7], (const float*)d_in[8],
        (const float*)d_in[9], (const float*)d_in[10]);
    build_Wt<<<720, 256, 0, stream>>>(W, Wh, Wl);

    for (int d0 = 0; d0 < 32; d0 += slabD) {
        basis_conv3<<<slabD * 16, 256, 0, stream>>>(x, z, tap, d0);
        gemm_gate<<<slabD * 8, 256, 0, stream>>>(z, Wh, Wl, x1, d0);
    }
    for (int d0 = 0; d0 < 32; d0 += slabD) {
        basis_conv3<<<slabD * 16, 256, 0, stream>>>(x1, z, tap, d0);
        gemm_gate<<<slabD * 8, 256, 0, stream>>>(z, Wh + 92160, Wl + 92160, x2, d0);
    }
    final_k<<<2048, 256, 0, stream>>>(x2, wls, wlv, wpos, out);
}

// Round 2
// 510.784 us; speedup vs baseline: 1.1788x; 1.0539x over previous
//
#include <hip/hip_runtime.h>
#include <math.h>

// x: [1,32,32,32,80] fp32 (80 = 32 scalars + 16 vec*3)
// conv: low-rank kernel basis 12 = 3 radial * {1, Yd, Yh, Yw}
// FUSED conv: per 64-voxel tile, 5 chunks of 16 ci:
//   halo->LDS -> tap-pair VALU -> z-chunk[64][192] in LDS -> split-bf16 MFMA
//   accumulate y[64][96] in regs -> gate -> xout.  z never touches HBM.
// out: [1,64,64,64,80] fp32

typedef __attribute__((ext_vector_type(8))) short bf16x8;
typedef __attribute__((ext_vector_type(4))) float f32x4;

__device__ __forceinline__ int eps3(int a, int m, int b) {
    if (a == b || a == m || m == b) return 0;
    return ((a==0&&m==1&&b==2)||(a==1&&m==2&&b==0)||(a==2&&m==0&&b==1)) ? 1 : -1;
}

// ---------------------------------------------------------------- tap-pair table
__global__ void build_tap(float* __restrict__ tap) {
    int t = threadIdx.x;
    if (t >= 125) return;
    int td = t / 25 - 2, th = (t / 5) % 5 - 2, tw = t % 5 - 2;
    int n2 = td*td + th*th + tw*tw;
    if (t == 62) {                       // center tap
        float* rec = tap + 40 * 16;
        rec[0] = __int_as_float(0); rec[1] = __int_as_float(0);
        for (int r = 0; r < 3; r++) {
            float tt = (0.f - 1.25f * (float)r) * 0.8f;
            rec[4 + r] = expf(-tt * tt);
        }
        return;
    }
    bool active = n2 <= 6;
    bool pos = (td > 0) || (td == 0 && th > 0) || (td == 0 && th == 0 && tw > 0);
    if (!(active && pos)) return;
    int idx = 0;                          // compact index among positive reps
    for (int q = 0; q < t; q++) {
        int qd = q / 25 - 2, qh = (q / 5) % 5 - 2, qw = q % 5 - 2;
        int m2 = qd*qd + qh*qh + qw*qw;
        bool p = (qd > 0) || (qd == 0 && qh > 0) || (qd == 0 && qh == 0 && qw > 0);
        if (m2 <= 6 && p) idx++;
    }
    float* rec = tap + idx * 16;
    rec[0] = __int_as_float((td+2)*120 + (th+2)*20 + (tw+2) - (2*120 + 2*20 + 2));
    rec[1] = __int_as_float((2-td)*120 + (2-th)*20 + (2-tw) - (2*120 + 2*20 + 2));
    float norm = sqrtf((float)n2);
    float comp[3] = {(float)td, (float)th, (float)tw};
    for (int r = 0; r < 3; r++) {
        float tt = (norm - 1.25f * (float)r) * 0.8f;
        float R = expf(-tt * tt);
        rec[4 + r] = R;
        for (int m = 0; m < 3; m++)
            rec[7 + r*3 + m] = R * 1.7320508075688772f * comp[m] / norm;
    }
}

// ---------------------------------------------------------------- W matrices (fp32 source)
// W[conv][j*80+ci][co], j = r*4+alpha.  2*12*80*96 = 184320 entries.
__global__ void build_W(float* __restrict__ W,
    const float* __restrict__ ss1, const float* __restrict__ sv1,
    const float* __restrict__ vs1, const float* __restrict__ vv01, const float* __restrict__ vv11,
    const float* __restrict__ ss2, const float* __restrict__ sv2,
    const float* __restrict__ vs2, const float* __restrict__ vv02, const float* __restrict__ vv12)
{
    int idx = threadIdx.x + blockIdx.x * 256;
    if (idx >= 184320) return;
    int conv = idx / 92160;
    int rem  = idx % 92160;
    int j  = rem / 7680;
    int ci = (rem / 96) % 80;
    int co = rem % 96;
    int r = j >> 2, al = j & 3;
    const float* ss  = conv ? ss2  : ss1;
    const float* sv  = conv ? sv2  : sv1;
    const float* vs  = conv ? vs2  : vs1;
    const float* vv0 = conv ? vv02 : vv01;
    const float* vv1 = conv ? vv12 : vv11;
    float val = 0.f;
    if (ci < 32) {
        if (co < 48) { if (al == 0) val = ss[(r*32 + ci)*48 + co]; }
        else {
            int o = (co - 48) / 3, m = (co - 48) % 3;
            if (al == m + 1) val = sv[(r*32 + ci)*16 + o];
        }
    } else {
        int i = (ci - 32) / 3, a = (ci - 32) % 3;
        if (co < 48) { if (al == a + 1) val = vs[(r*16 + i)*48 + co] * 0.5773502691896258f; }
        else {
            int o = (co - 48) / 3, b = (co - 48) % 3;
            if (al == 0) { if (a == b) val = vv0[(r*16 + i)*16 + o]; }
            else {
                int e = eps3(a, al - 1, b);
                if (e) val = vv1[(r*16 + i)*16 + o] * (float)e * 0.7071067811865476f;
            }
        }
    }
    W[idx] = val;
}

// ---------------------------------------------------------------- W split bf16 hi/lo, chunk-permuted
// Wc[conv][co][k'] with k' = c5*192 + j*16 + ci16  (ci = c5*16 + ci16, k = j*80+ci).
__global__ void build_Wc(const float* __restrict__ W,
                         unsigned short* __restrict__ Wh, unsigned short* __restrict__ Wl)
{
    int idx = threadIdx.x + blockIdx.x * 256;    // over 2*96*960
    if (idx >= 184320) return;
    int conv = idx / 92160, rem = idx % 92160;
    int co = rem / 960, kp = rem % 960;
    int c5 = kp / 192, r2 = kp % 192;
    int j = r2 / 16, ci16 = r2 % 16;
    int k = j * 80 + c5 * 16 + ci16;
    float w = W[conv * 92160 + k * 96 + co];
    unsigned int u = __float_as_uint(w);
    unsigned int hib = (u + 0x7FFFu + ((u >> 16) & 1u)) & 0xFFFF0000u;  // RNE bf16, as f32 bits
    float res = w - __uint_as_float(hib);
    unsigned int v = __float_as_uint(res);
    unsigned int lob = (v + 0x7FFFu + ((v >> 16) & 1u)) >> 16;
    Wh[idx] = (unsigned short)(hib >> 16);
    Wl[idx] = (unsigned short)lob;
}

// ---------------------------------------------------------------- fused conv (stage A + B)
__device__ __forceinline__ void split8(float4 a, float4 b, bf16x8& hi, bf16x8& lo) {
    float av[8] = {a.x, a.y, a.z, a.w, b.x, b.y, b.z, b.w};
    #pragma unroll
    for (int e = 0; e < 8; e++) {
        unsigned int u = __float_as_uint(av[e]);
        hi[e] = (short)(u >> 16);
        float res = av[e] - __uint_as_float(u & 0xFFFF0000u);
        lo[e] = (short)(__float_as_uint(res) >> 16);
    }
}

__global__ __launch_bounds__(256) void fused_conv(
    const float* __restrict__ xin, const unsigned short* __restrict__ Wh,
    const unsigned short* __restrict__ Wl, const float* __restrict__ tap,
    float* __restrict__ xout)
{
    __shared__ float xs[4][2880];        // halo: 720 pos x 16 ci = 46 KB
    __shared__ float zc[64][196];        // z chunk [64 v][192 k] +4 pad = 50 KB
    int tid = threadIdx.x;
    int cl = tid >> 6;                   // wave id = ci-group within chunk
    int vl64 = tid & 63;
    int dl = vl64 >> 5, hl = (vl64 >> 4) & 1, wl = vl64 & 15;
    int lr = vl64 & 15, lk = vl64 >> 4;  // MFMA lane decode
    int bid = blockIdx.x;
    int dt = (bid >> 5) << 1;
    int h0 = ((bid >> 1) & 15) << 1;
    int w0 = (bid & 1) << 4;

    // ---- precompute halo slots (chunk-invariant): 2880 float4 / 256 thr
    int gof[12];                         // float-index into xin (-1 = OOB)
    int lof[12];                         // float-index into xs flat
    #pragma unroll
    for (int q = 0; q < 12; q++) {
        int i = tid + q * 256;
        gof[q] = -1; lof[q] = 0;
        if (i < 2880) {
            int sl = i / 720, rr = i - sl * 720;
            int dd = rr / 120, rm = rr - dd * 120;
            int hh = rm / 20, ww = rm - hh * 20;
            int gd = dt + dd - 2, gh = h0 + hh - 2, gw = w0 + ww - 2;
            if (gd >= 0 && gd < 32 && gh >= 0 && gh < 32 && gw >= 0 && gw < 32)
                gof[q] = (((gd << 5) + gh) * 32 + gw) * 80 + sl * 4;
            lof[q] = sl * 2880 + rr * 4;
        }
    }
    float* xsf = &xs[0][0];

    // ---- prologue: load chunk 0 halo
    {
        float4 pf[12];
        #pragma unroll
        for (int q = 0; q < 12; q++) {
            int i = tid + q * 256;
            if (i < 2880)
                pf[q] = (gof[q] >= 0) ? *reinterpret_cast<const float4*>(xin + gof[q])
                                      : make_float4(0.f, 0.f, 0.f, 0.f);
        }
        #pragma unroll
        for (int q = 0; q < 12; q++) {
            int i = tid + q * 256;
            if (i < 2880) *reinterpret_cast<float4*>(xsf + lof[q]) = pf[q];
        }
    }
    __syncthreads();

    const f32x4 fzero = {0.f, 0.f, 0.f, 0.f};
    f32x4 acc[6];
    #pragma unroll
    for (int nt = 0; nt < 6; nt++) acc[nt] = fzero;

    for (int c5 = 0; c5 < 5; c5++) {
        // -- issue prefetch for next chunk (hidden under stage-A VALU)
        float4 pf[12];
        if (c5 < 4) {
            int chof = (c5 + 1) * 16;
            #pragma unroll
            for (int q = 0; q < 12; q++) {
                int i = tid + q * 256;
                if (i < 2880)
                    pf[q] = (gof[q] >= 0) ? *reinterpret_cast<const float4*>(xin + gof[q] + chof)
                                          : make_float4(0.f, 0.f, 0.f, 0.f);
            }
        }
        // -- stage A: tap-pair conv for this thread's (voxel, ci-group) -> zc
        {
            const float* xp = &xs[cl][((dl + 2) * 120 + (hl + 2) * 20 + (wl + 2)) * 4];
            float az[12][4];
            #pragma unroll
            for (int j = 0; j < 12; j++)
                #pragma unroll
                for (int c = 0; c < 4; c++) az[j][c] = 0.f;
            {   // center
                const float* rec = tap + 640;
                float4 xc = *reinterpret_cast<const float4*>(xp);
                #pragma unroll
                for (int r = 0; r < 3; r++) {
                    float R = rec[4 + r];
                    az[r*4][0] += R * xc.x; az[r*4][1] += R * xc.y;
                    az[r*4][2] += R * xc.z; az[r*4][3] += R * xc.w;
                }
            }
            for (int p = 0; p < 40; p++) {
                const float* rec = tap + p * 16;
                int op = __float_as_int(rec[0]) * 4, om = __float_as_int(rec[1]) * 4;
                float4 xa = *reinterpret_cast<const float4*>(xp + op);
                float4 xb = *reinterpret_cast<const float4*>(xp + om);
                float s[4], d[4];
                s[0] = xa.x + xb.x; s[1] = xa.y + xb.y; s[2] = xa.z + xb.z; s[3] = xa.w + xb.w;
                d[0] = xa.x - xb.x; d[1] = xa.y - xb.y; d[2] = xa.z - xb.z; d[3] = xa.w - xb.w;
                #pragma unroll
                for (int r = 0; r < 3; r++) {
                    float R = rec[4 + r];
                    #pragma unroll
                    for (int c = 0; c < 4; c++) az[r*4][c] += R * s[c];
                    #pragma unroll
                    for (int m = 0; m < 3; m++) {
                        float RY = rec[7 + r*3 + m];
                        #pragma unroll
                        for (int c = 0; c < 4; c++) az[r*4 + m + 1][c] += RY * d[c];
                    }
                }
            }
            #pragma unroll
            for (int j = 0; j < 12; j++)
                *reinterpret_cast<float4*>(&zc[vl64][j * 16 + cl * 4]) =
                    make_float4(az[j][0], az[j][1], az[j][2], az[j][3]);
        }
        __syncthreads();                 // zc ready; xs reads done
        // -- write prefetched halo into xs (overlaps MFMA below)
        if (c5 < 4) {
            #pragma unroll
            for (int q = 0; q < 12; q++) {
                int i = tid + q * 256;
                if (i < 2880) *reinterpret_cast<float4*>(xsf + lof[q]) = pf[q];
            }
        }
        // -- stage B: MFMA over this chunk's 192 k  (wave cl handles rows cl*16..+15)
        #pragma unroll
        for (int ks = 0; ks < 6; ks++) {
            const unsigned short* bbh = Wh + lr * 960 + c5 * 192 + ks * 32 + lk * 8;
            const unsigned short* bbl = Wl + lr * 960 + c5 * 192 + ks * 32 + lk * 8;
            bf16x8 bh[6], bl[6];
            #pragma unroll
            for (int nt = 0; nt < 6; nt++) {
                bh[nt] = *reinterpret_cast<const bf16x8*>(bbh + nt * 15360);
                bl[nt] = *reinterpret_cast<const bf16x8*>(bbl + nt * 15360);
            }
            const float* ap = &zc[cl * 16 + lr][ks * 32 + lk * 8];
            bf16x8 ah, al;
            split8(*reinterpret_cast<const float4*>(ap),
                   *reinterpret_cast<const float4*>(ap + 4), ah, al);
            #pragma unroll
            for (int nt = 0; nt < 6; nt++) {
                acc[nt] = __builtin_amdgcn_mfma_f32_16x16x32_bf16(ah, bh[nt], acc[nt], 0, 0, 0);
                acc[nt] = __builtin_amdgcn_mfma_f32_16x16x32_bf16(al, bh[nt], acc[nt], 0, 0, 0);
                acc[nt] = __builtin_amdgcn_mfma_f32_16x16x32_bf16(ah, bl[nt], acc[nt], 0, 0, 0);
            }
        }
        __syncthreads();                 // zc consumed; xs writes visible for next stage A
    }

    // ---- epilogue: y -> gate -> store (reuse xs as y[64][97])
    float* y = xsf;
    // C/D layout: col = lane&15, row = (lane>>4)*4 + reg  (rows within wave's 16)
    #pragma unroll
    for (int nt = 0; nt < 6; nt++)
        #pragma unroll
        for (int r = 0; r < 4; r++)
            y[(cl * 16 + lk * 4 + r) * 97 + nt * 16 + lr] = acc[nt][r];
    __syncthreads();
    for (int idx = tid; idx < 64 * 80; idx += 256) {
        int vr = idx / 80, c = idx % 80;
        int gd = dt + (vr >> 5), gh = h0 + ((vr >> 4) & 1), gw = w0 + (vr & 15);
        const float* yr = y + vr * 97;
        float val;
        if (c < 32) val = fmaxf(yr[c], 0.f);
        else {
            int q = c - 32;
            float g = 1.f / (1.f + __expf(-yr[32 + q / 3]));
            val = yr[48 + q] * g;
        }
        xout[(size_t)(((gd << 5) + gh) * 32 + gw) * 80 + c] = val;
    }
}

// ---------------------------------------------------------------- Final head (unchanged)
__global__ __launch_bounds__(256) void final_k(
    const float* __restrict__ x2, const float* __restrict__ wls,
    const float* __restrict__ wlv, const float* __restrict__ wpos,
    float* __restrict__ out)
{
    __shared__ float xv[16 * 81];
    __shared__ float coeff[16 * 161];
    __shared__ float s_wls[512];
    __shared__ float s_wlv[768];
    int t = threadIdx.x;
    int bid = blockIdx.x;
    int cw0 = (bid & 1) * 16;
    int ch  = (bid >> 1) & 31;
    int cd  = bid >> 6;
    float wp = wpos[0];
    {
        int base = ((cd * 32 + ch) * 32 + cw0) * 80;
        #pragma unroll
        for (int i = t; i < 1280; i += 256) {
            int vi = i / 80, c = i % 80;
            xv[vi * 81 + c] = x2[base + i];
        }
        for (int i = t; i < 512; i += 256) s_wls[i] = wls[i];
        for (int i = t; i < 768; i += 256) s_wlv[i] = wlv[i];
    }
    __syncthreads();
    {
        int vi = t >> 4, j = t & 15;
        const float* xp = xv + vi * 81;
        float* cf = coeff + vi * 161;
        #pragma unroll
        for (int l = 0; l < 10; l++) {
            int q = l * 16 + j;
            float sum = 0.f;
            if (q < 96) {
                int o = q / 3, m = q % 3;
                #pragma unroll
                for (int c = 0; c < 16; c++) sum += xp[32 + c * 3 + m] * s_wls[c * 32 + o];
            } else if (q < 112) {
                int o = q - 96;
                #pragma unroll
                for (int c = 0; c < 32; c++) sum += xp[c] * s_wlv[c * 16 + o];
            } else {
                int q2 = q - 112; int o = q2 / 3, m = q2 % 3;
                #pragma unroll
                for (int c = 0; c < 16; c++) sum += xp[32 + c * 3 + m] * s_wlv[(32 + c) * 16 + o];
            }
            cf[q] = sum;
        }
    }
    __syncthreads();
    const float scale = 0.14433756729740643f;
    #pragma unroll
    for (int f01 = 0; f01 < 4; f01++) {
        int fd = 2 * cd + (f01 >> 1), fh = 2 * ch + (f01 & 1);
        float p0 = wp * (float)(cd + (f01 >> 1) - 16);
        float p1 = wp * (float)(ch + (f01 & 1) - 16);
        size_t obase = (size_t)((fd * 64 + fh) * 64 + cw0 * 2) * 80;
        #pragma unroll
        for (int it = 0; it < 10; it++) {
            int idx = it * 256 + t;
            int fwl = idx / 80, c = idx - fwl * 80;
            int vi = fwl >> 1;
            float p2 = wp * (float)(cw0 + vi + (fwl & 1) - 16);
            const float* cf = coeff + vi * 161;
            float val;
            if (c < 32) {
                val = cf[c * 3] * p0 + cf[c * 3 + 1] * p1 + cf[c * 3 + 2] * p2;
            } else {
                int q = c - 32, o = q / 3, m = q - o * 3;
                float A = cf[96 + o];
                const float* w2 = cf + 112 + o * 3;
                float pm, crm;
                if (m == 0)      { pm = p0; crm = w2[1] * p2 - w2[2] * p1; }
                else if (m == 1) { pm = p1; crm = w2[2] * p0 - w2[0] * p2; }
                else             { pm = p2; crm = w2[0] * p1 - w2[1] * p0; }
                val = A * pm + crm * 0.7071067811865476f;
            }
            out[obase + idx] = val * scale;
        }
    }
}

// ----------------------------------------------------------------
extern "C" void kernel_launch(void* const* d_in, const int* in_sizes, int n_in,
                              void* d_out, int out_size, void* d_ws, size_t ws_size,
                              hipStream_t stream)
{
    const float* x    = (const float*)d_in[0];
    const float* wpos = (const float*)d_in[11];
    const float* wls  = (const float*)d_in[12];
    const float* wlv  = (const float*)d_in[13];
    float* out = (float*)d_out;
    float* ws  = (float*)d_ws;

    float* tap = ws;                        // 656 floats -> pad 1024
    float* W   = ws + 1024;                 // 184320 fp32
    unsigned short* Wh = (unsigned short*)(ws + 1024 + 184320);   // 184320 ushorts
    unsigned short* Wl = Wh + 184320;                              // 184320 ushorts
    float* x1  = ws + 1024 + 184320 + 184320;   // (2 ushort arrays = 184320 floats)
    float* x2  = x1 + 2621440;

    build_tap<<<1, 128, 0, stream>>>(tap);
    build_W<<<720, 256, 0, stream>>>(W,
        (const float*)d_in[1], (const float*)d_in[2], (const float*)d_in[3],
        (const float*)d_in[4], (const float*)d_in[5],
        (const float*)d_in[6], (const float*)d_in[7], (const float*)d_in[8],
        (const float*)d_in[9], (const float*)d_in[10]);
    build_Wc<<<720, 256, 0, stream>>>(W, Wh, Wl);

    fused_conv<<<512, 256, 0, stream>>>(x,  Wh,         Wl,         tap, x1);
    fused_conv<<<512, 256, 0, stream>>>(x1, Wh + 92160, Wl + 92160, tap, x2);
    final_k<<<2048, 256, 0, stream>>>(x2, wls, wlv, wpos, out);
}

// Round 3
// 419.857 us; speedup vs baseline: 1.4341x; 1.2166x over previous
//
#include <hip/hip_runtime.h>
#include <math.h>

// x: [1,32,32,32,80] fp32 (80 = 32 scalars + 16 vec*3)
// conv: low-rank kernel basis 12 = 3 radial * {1, Yd, Yh, Yw}
// FUSED conv, 8-wave blocks: per 128-voxel tile (4x4x8), 5 chunks of 16 ci:
//   halo->LDS -> tap-pair VALU -> z-chunk[128][204] in LDS -> split-bf16 MFMA
//   accumulate y[128][96] in regs -> gate -> xout.  z never touches HBM.
// Grid 256 = 1 block/CU, 8 waves = 2/SIMD.  LDS 153.6 KB.
// out: [1,64,64,64,80] fp32

typedef __attribute__((ext_vector_type(8))) short bf16x8;
typedef __attribute__((ext_vector_type(4))) float f32x4;

__device__ __forceinline__ int eps3(int a, int m, int b) {
    if (a == b || a == m || m == b) return 0;
    return ((a==0&&m==1&&b==2)||(a==1&&m==2&&b==0)||(a==2&&m==0&&b==1)) ? 1 : -1;
}

// ---------------------------------------------------------------- tap-pair table
// offsets now in 8x8x12 halo pos-units (d:96, h:12, w:1)
__global__ void build_tap(float* __restrict__ tap) {
    int t = threadIdx.x;
    if (t >= 125) return;
    int td = t / 25 - 2, th = (t / 5) % 5 - 2, tw = t % 5 - 2;
    int n2 = td*td + th*th + tw*tw;
    if (t == 62) {                       // center tap
        float* rec = tap + 40 * 16;
        rec[0] = __int_as_float(0); rec[1] = __int_as_float(0);
        for (int r = 0; r < 3; r++) {
            float tt = (0.f - 1.25f * (float)r) * 0.8f;
            rec[4 + r] = expf(-tt * tt);
        }
        return;
    }
    bool active = n2 <= 6;
    bool pos = (td > 0) || (td == 0 && th > 0) || (td == 0 && th == 0 && tw > 0);
    if (!(active && pos)) return;
    int idx = 0;                          // compact index among positive reps
    for (int q = 0; q < t; q++) {
        int qd = q / 25 - 2, qh = (q / 5) % 5 - 2, qw = q % 5 - 2;
        int m2 = qd*qd + qh*qh + qw*qw;
        bool p = (qd > 0) || (qd == 0 && qh > 0) || (qd == 0 && qh == 0 && qw > 0);
        if (m2 <= 6 && p) idx++;
    }
    float* rec = tap + idx * 16;
    int off = td * 96 + th * 12 + tw;
    rec[0] = __int_as_float(off);
    rec[1] = __int_as_float(-off);
    float norm = sqrtf((float)n2);
    float comp[3] = {(float)td, (float)th, (float)tw};
    for (int r = 0; r < 3; r++) {
        float tt = (norm - 1.25f * (float)r) * 0.8f;
        float R = expf(-tt * tt);
        rec[4 + r] = R;
        for (int m = 0; m < 3; m++)
            rec[7 + r*3 + m] = R * 1.7320508075688772f * comp[m] / norm;
    }
}

// ---------------------------------------------------------------- W matrices (fp32 source)
// W[conv][j*80+ci][co], j = r*4+alpha.  2*12*80*96 = 184320 entries.
__global__ void build_W(float* __restrict__ W,
    const float* __restrict__ ss1, const float* __restrict__ sv1,
    const float* __restrict__ vs1, const float* __restrict__ vv01, const float* __restrict__ vv11,
    const float* __restrict__ ss2, const float* __restrict__ sv2,
    const float* __restrict__ vs2, const float* __restrict__ vv02, const float* __restrict__ vv12)
{
    int idx = threadIdx.x + blockIdx.x * 256;
    if (idx >= 184320) return;
    int conv = idx / 92160;
    int rem  = idx % 92160;
    int j  = rem / 7680;
    int ci = (rem / 96) % 80;
    int co = rem % 96;
    int r = j >> 2, al = j & 3;
    const float* ss  = conv ? ss2  : ss1;
    const float* sv  = conv ? sv2  : sv1;
    const float* vs  = conv ? vs2  : vs1;
    const float* vv0 = conv ? vv02 : vv01;
    const float* vv1 = conv ? vv12 : vv11;
    float val = 0.f;
    if (ci < 32) {
        if (co < 48) { if (al == 0) val = ss[(r*32 + ci)*48 + co]; }
        else {
            int o = (co - 48) / 3, m = (co - 48) % 3;
            if (al == m + 1) val = sv[(r*32 + ci)*16 + o];
        }
    } else {
        int i = (ci - 32) / 3, a = (ci - 32) % 3;
        if (co < 48) { if (al == a + 1) val = vs[(r*16 + i)*48 + co] * 0.5773502691896258f; }
        else {
            int o = (co - 48) / 3, b = (co - 48) % 3;
            if (al == 0) { if (a == b) val = vv0[(r*16 + i)*16 + o]; }
            else {
                int e = eps3(a, al - 1, b);
                if (e) val = vv1[(r*16 + i)*16 + o] * (float)e * 0.7071067811865476f;
            }
        }
    }
    W[idx] = val;
}

// ---------------------------------------------------------------- W split bf16 hi/lo, chunk-permuted
// Wc[conv][co][k'] with k' = c5*192 + j*16 + ci16  (ci = c5*16 + ci16, k = j*80+ci).
__global__ void build_Wc(const float* __restrict__ W,
                         unsigned short* __restrict__ Wh, unsigned short* __restrict__ Wl)
{
    int idx = threadIdx.x + blockIdx.x * 256;    // over 2*96*960
    if (idx >= 184320) return;
    int conv = idx / 92160, rem = idx % 92160;
    int co = rem / 960, kp = rem % 960;
    int c5 = kp / 192, r2 = kp % 192;
    int j = r2 / 16, ci16 = r2 % 16;
    int k = j * 80 + c5 * 16 + ci16;
    float w = W[conv * 92160 + k * 96 + co];
    unsigned int u = __float_as_uint(w);
    unsigned int hib = (u + 0x7FFFu + ((u >> 16) & 1u)) & 0xFFFF0000u;  // RNE bf16, as f32 bits
    float res = w - __uint_as_float(hib);
    unsigned int v = __float_as_uint(res);
    unsigned int lob = (v + 0x7FFFu + ((v >> 16) & 1u)) >> 16;
    Wh[idx] = (unsigned short)(hib >> 16);
    Wl[idx] = (unsigned short)lob;
}

// ---------------------------------------------------------------- fused conv (stage A + B)
__device__ __forceinline__ void split8(float4 a, float4 b, bf16x8& hi, bf16x8& lo) {
    float av[8] = {a.x, a.y, a.z, a.w, b.x, b.y, b.z, b.w};
    #pragma unroll
    for (int e = 0; e < 8; e++) {
        unsigned int u = __float_as_uint(av[e]);
        hi[e] = (short)(u >> 16);
        float res = av[e] - __uint_as_float(u & 0xFFFF0000u);
        lo[e] = (short)(__float_as_uint(res) >> 16);
    }
}

__global__ __launch_bounds__(512, 2) void fused_conv(
    const float* __restrict__ xin, const unsigned short* __restrict__ Wh,
    const unsigned short* __restrict__ Wl, const float* __restrict__ tap,
    float* __restrict__ xout)
{
    // smem: [0,12288)  halo xs: 4 sl x 768 pos x 4 ci        (49.2 KB)
    //       [12288,38400) zc[128][204] (204%32=12 -> conflict-free b128)  (104.4 KB)
    // epilogue reuses [0,12544) as y[128][98]
    __shared__ float smem[38400];
    int tid = threadIdx.x;
    int cl = tid >> 7;                   // ci-group 0..3 (stage A)
    int vl = tid & 127;                  // voxel-in-tile (stage A)
    int dl = vl >> 5, hl = (vl >> 3) & 3, wl = vl & 7;
    int w8 = tid >> 6, l = tid & 63;     // MFMA wave/lane decode
    int lr = l & 15, lk = l >> 4;
    int bid = blockIdx.x;
    int dt = (bid >> 5) << 2;
    int h0 = ((bid >> 2) & 7) << 2;
    int w0 = (bid & 3) << 3;

    // ---- precompute halo slots (chunk-invariant): 3072 float4 / 512 thr = 6 each
    int gof[6];                          // float-index into xin (-1 = OOB)
    int lof[6];                          // float-index into smem (xs region)
    #pragma unroll
    for (int q = 0; q < 6; q++) {
        int i = tid + q * 512;
        int sl = i / 768, rr = i - sl * 768;
        int dd = rr / 96, rm = rr - dd * 96;
        int hh = rm / 12, ww = rm - hh * 12;
        int gd = dt + dd - 2, gh = h0 + hh - 2, gw = w0 + ww - 2;
        gof[q] = (gd >= 0 && gd < 32 && gh >= 0 && gh < 32 && gw >= 0 && gw < 32)
               ? (((gd << 5) + gh) * 32 + gw) * 80 + sl * 4 : -1;
        lof[q] = sl * 3072 + rr * 4;
    }

    // ---- prologue: load chunk 0 halo
    {
        float4 pf[6];
        #pragma unroll
        for (int q = 0; q < 6; q++)
            pf[q] = (gof[q] >= 0) ? *reinterpret_cast<const float4*>(xin + gof[q])
                                  : make_float4(0.f, 0.f, 0.f, 0.f);
        #pragma unroll
        for (int q = 0; q < 6; q++)
            *reinterpret_cast<float4*>(smem + lof[q]) = pf[q];
    }
    __syncthreads();

    const f32x4 fzero = {0.f, 0.f, 0.f, 0.f};
    f32x4 acc[6];
    #pragma unroll
    for (int nt = 0; nt < 6; nt++) acc[nt] = fzero;

    float* zcb = smem + 12288;
    const float* xp = smem + cl * 3072 + (((dl + 2) * 8 + hl + 2) * 12 + (wl + 2)) * 4;
    float* zp = zcb + vl * 204;

    for (int c5 = 0; c5 < 5; c5++) {
        // -- issue prefetch for next chunk (hidden under stage-A VALU)
        float4 pf[6];
        if (c5 < 4) {
            int chof = (c5 + 1) * 16;
            #pragma unroll
            for (int q = 0; q < 6; q++)
                pf[q] = (gof[q] >= 0) ? *reinterpret_cast<const float4*>(xin + gof[q] + chof)
                                      : make_float4(0.f, 0.f, 0.f, 0.f);
        }
        // -- stage A: tap-pair conv for (voxel vl, ci-group cl) -> zc
        {
            float az[12][4];
            #pragma unroll
            for (int j = 0; j < 12; j++)
                #pragma unroll
                for (int c = 0; c < 4; c++) az[j][c] = 0.f;
            {   // center
                const float* rec = tap + 640;
                float4 xc = *reinterpret_cast<const float4*>(xp);
                #pragma unroll
                for (int r = 0; r < 3; r++) {
                    float R = rec[4 + r];
                    az[r*4][0] += R * xc.x; az[r*4][1] += R * xc.y;
                    az[r*4][2] += R * xc.z; az[r*4][3] += R * xc.w;
                }
            }
            for (int p = 0; p < 40; p++) {
                const float* rec = tap + p * 16;
                int op = __float_as_int(rec[0]) * 4, om = __float_as_int(rec[1]) * 4;
                float4 xa = *reinterpret_cast<const float4*>(xp + op);
                float4 xb = *reinterpret_cast<const float4*>(xp + om);
                float s[4], d[4];
                s[0] = xa.x + xb.x; s[1] = xa.y + xb.y; s[2] = xa.z + xb.z; s[3] = xa.w + xb.w;
                d[0] = xa.x - xb.x; d[1] = xa.y - xb.y; d[2] = xa.z - xb.z; d[3] = xa.w - xb.w;
                #pragma unroll
                for (int r = 0; r < 3; r++) {
                    float R = rec[4 + r];
                    #pragma unroll
                    for (int c = 0; c < 4; c++) az[r*4][c] += R * s[c];
                    #pragma unroll
                    for (int m = 0; m < 3; m++) {
                        float RY = rec[7 + r*3 + m];
                        #pragma unroll
                        for (int c = 0; c < 4; c++) az[r*4 + m + 1][c] += RY * d[c];
                    }
                }
            }
            #pragma unroll
            for (int j = 0; j < 12; j++)
                *reinterpret_cast<float4*>(zp + j * 16 + cl * 4) =
                    make_float4(az[j][0], az[j][1], az[j][2], az[j][3]);
        }
        __syncthreads();                 // zc ready; xs reads done
        // -- write prefetched halo into xs (overlaps MFMA below)
        if (c5 < 4) {
            #pragma unroll
            for (int q = 0; q < 6; q++)
                *reinterpret_cast<float4*>(smem + lof[q]) = pf[q];
        }
        // -- stage B: MFMA over this chunk's 192 k  (wave w8 owns rows w8*16..+15)
        const float* ap0 = zcb + (w8 * 16 + lr) * 204 + lk * 8;
        #pragma unroll
        for (int ks = 0; ks < 6; ks++) {
            const unsigned short* bbh = Wh + lr * 960 + c5 * 192 + ks * 32 + lk * 8;
            const unsigned short* bbl = Wl + lr * 960 + c5 * 192 + ks * 32 + lk * 8;
            bf16x8 bh[6], bl[6];
            #pragma unroll
            for (int nt = 0; nt < 6; nt++) {
                bh[nt] = *reinterpret_cast<const bf16x8*>(bbh + nt * 15360);
                bl[nt] = *reinterpret_cast<const bf16x8*>(bbl + nt * 15360);
            }
            const float* ap = ap0 + ks * 32;
            bf16x8 ah, al;
            split8(*reinterpret_cast<const float4*>(ap),
                   *reinterpret_cast<const float4*>(ap + 4), ah, al);
            #pragma unroll
            for (int nt = 0; nt < 6; nt++) {
                acc[nt] = __builtin_amdgcn_mfma_f32_16x16x32_bf16(ah, bh[nt], acc[nt], 0, 0, 0);
                acc[nt] = __builtin_amdgcn_mfma_f32_16x16x32_bf16(al, bh[nt], acc[nt], 0, 0, 0);
                acc[nt] = __builtin_amdgcn_mfma_f32_16x16x32_bf16(ah, bl[nt], acc[nt], 0, 0, 0);
            }
        }
        __syncthreads();                 // zc reads done; xs writes visible
    }

    // ---- epilogue: y -> gate -> store (reuse smem as y[128][98])
    float* y = smem;
    // C/D layout: col = lane&15, row = (lane>>4)*4 + reg
    #pragma unroll
    for (int nt = 0; nt < 6; nt++)
        #pragma unroll
        for (int r = 0; r < 4; r++)
            y[(w8 * 16 + lk * 4 + r) * 98 + nt * 16 + lr] = acc[nt][r];
    __syncthreads();
    #pragma unroll
    for (int it = 0; it < 20; it++) {
        int idx = tid + it * 512;
        int vr = idx / 80, c = idx - vr * 80;
        int gd = dt + (vr >> 5), gh = h0 + ((vr >> 3) & 3), gw = w0 + (vr & 7);
        const float* yr = y + vr * 98;
        float val;
        if (c < 32) val = fmaxf(yr[c], 0.f);
        else {
            int q = c - 32;
            float g = 1.f / (1.f + __expf(-yr[32 + q / 3]));
            val = yr[48 + q] * g;
        }
        xout[(size_t)(((gd << 5) + gh) * 32 + gw) * 80 + c] = val;
    }
}

// ---------------------------------------------------------------- Final head (unchanged)
__global__ __launch_bounds__(256) void final_k(
    const float* __restrict__ x2, const float* __restrict__ wls,
    const float* __restrict__ wlv, const float* __restrict__ wpos,
    float* __restrict__ out)
{
    __shared__ float xv[16 * 81];
    __shared__ float coeff[16 * 161];
    __shared__ float s_wls[512];
    __shared__ float s_wlv[768];
    int t = threadIdx.x;
    int bid = blockIdx.x;
    int cw0 = (bid & 1) * 16;
    int ch  = (bid >> 1) & 31;
    int cd  = bid >> 6;
    float wp = wpos[0];
    {
        int base = ((cd * 32 + ch) * 32 + cw0) * 80;
        #pragma unroll
        for (int i = t; i < 1280; i += 256) {
            int vi = i / 80, c = i % 80;
            xv[vi * 81 + c] = x2[base + i];
        }
        for (int i = t; i < 512; i += 256) s_wls[i] = wls[i];
        for (int i = t; i < 768; i += 256) s_wlv[i] = wlv[i];
    }
    __syncthreads();
    {
        int vi = t >> 4, j = t & 15;
        const float* xp = xv + vi * 81;
        float* cf = coeff + vi * 161;
        #pragma unroll
        for (int l = 0; l < 10; l++) {
            int q = l * 16 + j;
            float sum = 0.f;
            if (q < 96) {
                int o = q / 3, m = q % 3;
                #pragma unroll
                for (int c = 0; c < 16; c++) sum += xp[32 + c * 3 + m] * s_wls[c * 32 + o];
            } else if (q < 112) {
                int o = q - 96;
                #pragma unroll
                for (int c = 0; c < 32; c++) sum += xp[c] * s_wlv[c * 16 + o];
            } else {
                int q2 = q - 112; int o = q2 / 3, m = q2 % 3;
                #pragma unroll
                for (int c = 0; c < 16; c++) sum += xp[32 + c * 3 + m] * s_wlv[(32 + c) * 16 + o];
            }
            cf[q] = sum;
        }
    }
    __syncthreads();
    const float scale = 0.14433756729740643f;
    #pragma unroll
    for (int f01 = 0; f01 < 4; f01++) {
        int fd = 2 * cd + (f01 >> 1), fh = 2 * ch + (f01 & 1);
        float p0 = wp * (float)(cd + (f01 >> 1) - 16);
        float p1 = wp * (float)(ch + (f01 & 1) - 16);
        size_t obase = (size_t)((fd * 64 + fh) * 64 + cw0 * 2) * 80;
        #pragma unroll
        for (int it = 0; it < 10; it++) {
            int idx = it * 256 + t;
            int fwl = idx / 80, c = idx - fwl * 80;
            int vi = fwl >> 1;
            float p2 = wp * (float)(cw0 + vi + (fwl & 1) - 16);
            const float* cf = coeff + vi * 161;
            float val;
            if (c < 32) {
                val = cf[c * 3] * p0 + cf[c * 3 + 1] * p1 + cf[c * 3 + 2] * p2;
            } else {
                int q = c - 32, o = q / 3, m = q - o * 3;
                float A = cf[96 + o];
                const float* w2 = cf + 112 + o * 3;
                float pm, crm;
                if (m == 0)      { pm = p0; crm = w2[1] * p2 - w2[2] * p1; }
                else if (m == 1) { pm = p1; crm = w2[2] * p0 - w2[0] * p2; }
                else             { pm = p2; crm = w2[0] * p1 - w2[1] * p0; }
                val = A * pm + crm * 0.7071067811865476f;
            }
            out[obase + idx] = val * scale;
        }
    }
}

// ----------------------------------------------------------------
extern "C" void kernel_launch(void* const* d_in, const int* in_sizes, int n_in,
                              void* d_out, int out_size, void* d_ws, size_t ws_size,
                              hipStream_t stream)
{
    const float* x    = (const float*)d_in[0];
    const float* wpos = (const float*)d_in[11];
    const float* wls  = (const float*)d_in[12];
    const float* wlv  = (const float*)d_in[13];
    float* out = (float*)d_out;
    float* ws  = (float*)d_ws;

    float* tap = ws;                        // 656 floats -> pad 1024
    float* W   = ws + 1024;                 // 184320 fp32
    unsigned short* Wh = (unsigned short*)(ws + 1024 + 184320);   // 184320 ushorts
    unsigned short* Wl = Wh + 184320;                              // 184320 ushorts
    float* x1  = ws + 1024 + 184320 + 184320;   // (2 ushort arrays = 184320 floats)
    float* x2  = x1 + 2621440;

    build_tap<<<1, 128, 0, stream>>>(tap);
    build_W<<<720, 256, 0, stream>>>(W,
        (const float*)d_in[1], (const float*)d_in[2], (const float*)d_in[3],
        (const float*)d_in[4], (const float*)d_in[5],
        (const float*)d_in[6], (const float*)d_in[7], (const float*)d_in[8],
        (const float*)d_in[9], (const float*)d_in[10]);
    build_Wc<<<720, 256, 0, stream>>>(W, Wh, Wl);

    fused_conv<<<256, 512, 0, stream>>>(x,  Wh,         Wl,         tap, x1);
    fused_conv<<<256, 512, 0, stream>>>(x1, Wh + 92160, Wl + 92160, tap, x2);
    final_k<<<2048, 256, 0, stream>>>(x2, wls, wlv, wpos, out);
}

// Round 4
// 411.321 us; speedup vs baseline: 1.4639x; 1.0208x over previous
//
#include <hip/hip_runtime.h>
#include <math.h>

// x: [1,32,32,32,80] fp32 (80 = 32 scalars + 16 vec*3)
// conv: low-rank kernel basis 12 = 3 radial * {1, Yd, Yh, Yw}
// FUSED conv, 16-wave blocks (1024 thr): per 128-voxel tile (4x4x8), 5 chunks of 16 ci:
//   halo->LDS -> tap-pair VALU (1 vox x 2 ci per lane) -> zc[128][196] in LDS ->
//   split-bf16 MFMA (wave = 16-row tile x co-half) -> gate -> xout.
// Grid 256 = 1 block/CU, 16 waves = 4/SIMD.  LDS 149.5 KB.
// out: [1,64,64,64,80] fp32

typedef __attribute__((ext_vector_type(8))) short bf16x8;
typedef __attribute__((ext_vector_type(4))) float f32x4;

__device__ __forceinline__ int eps3(int a, int m, int b) {
    if (a == b || a == m || m == b) return 0;
    return ((a==0&&m==1&&b==2)||(a==1&&m==2&&b==0)||(a==2&&m==0&&b==1)) ? 1 : -1;
}

// ---------------------------------------------------------------- tap-pair table
// offsets in 8x8x12 halo pos-units (d:96, h:12, w:1)
__global__ void build_tap(float* __restrict__ tap) {
    int t = threadIdx.x;
    if (t >= 125) return;
    int td = t / 25 - 2, th = (t / 5) % 5 - 2, tw = t % 5 - 2;
    int n2 = td*td + th*th + tw*tw;
    if (t == 62) {                       // center tap
        float* rec = tap + 40 * 16;
        rec[0] = __int_as_float(0); rec[1] = __int_as_float(0);
        for (int r = 0; r < 3; r++) {
            float tt = (0.f - 1.25f * (float)r) * 0.8f;
            rec[4 + r] = expf(-tt * tt);
        }
        return;
    }
    bool active = n2 <= 6;
    bool pos = (td > 0) || (td == 0 && th > 0) || (td == 0 && th == 0 && tw > 0);
    if (!(active && pos)) return;
    int idx = 0;                          // compact index among positive reps
    for (int q = 0; q < t; q++) {
        int qd = q / 25 - 2, qh = (q / 5) % 5 - 2, qw = q % 5 - 2;
        int m2 = qd*qd + qh*qh + qw*qw;
        bool p = (qd > 0) || (qd == 0 && qh > 0) || (qd == 0 && qh == 0 && qw > 0);
        if (m2 <= 6 && p) idx++;
    }
    float* rec = tap + idx * 16;
    int off = td * 96 + th * 12 + tw;
    rec[0] = __int_as_float(off);
    rec[1] = __int_as_float(-off);
    float norm = sqrtf((float)n2);
    float comp[3] = {(float)td, (float)th, (float)tw};
    for (int r = 0; r < 3; r++) {
        float tt = (norm - 1.25f * (float)r) * 0.8f;
        float R = expf(-tt * tt);
        rec[4 + r] = R;
        for (int m = 0; m < 3; m++)
            rec[7 + r*3 + m] = R * 1.7320508075688772f * comp[m] / norm;
    }
}

// ---------------------------------------------------------------- W matrices (fp32 source)
// W[conv][j*80+ci][co], j = r*4+alpha.  2*12*80*96 = 184320 entries.
__global__ void build_W(float* __restrict__ W,
    const float* __restrict__ ss1, const float* __restrict__ sv1,
    const float* __restrict__ vs1, const float* __restrict__ vv01, const float* __restrict__ vv11,
    const float* __restrict__ ss2, const float* __restrict__ sv2,
    const float* __restrict__ vs2, const float* __restrict__ vv02, const float* __restrict__ vv12)
{
    int idx = threadIdx.x + blockIdx.x * 256;
    if (idx >= 184320) return;
    int conv = idx / 92160;
    int rem  = idx % 92160;
    int j  = rem / 7680;
    int ci = (rem / 96) % 80;
    int co = rem % 96;
    int r = j >> 2, al = j & 3;
    const float* ss  = conv ? ss2  : ss1;
    const float* sv  = conv ? sv2  : sv1;
    const float* vs  = conv ? vs2  : vs1;
    const float* vv0 = conv ? vv02 : vv01;
    const float* vv1 = conv ? vv12 : vv11;
    float val = 0.f;
    if (ci < 32) {
        if (co < 48) { if (al == 0) val = ss[(r*32 + ci)*48 + co]; }
        else {
            int o = (co - 48) / 3, m = (co - 48) % 3;
            if (al == m + 1) val = sv[(r*32 + ci)*16 + o];
        }
    } else {
        int i = (ci - 32) / 3, a = (ci - 32) % 3;
        if (co < 48) { if (al == a + 1) val = vs[(r*16 + i)*48 + co] * 0.5773502691896258f; }
        else {
            int o = (co - 48) / 3, b = (co - 48) % 3;
            if (al == 0) { if (a == b) val = vv0[(r*16 + i)*16 + o]; }
            else {
                int e = eps3(a, al - 1, b);
                if (e) val = vv1[(r*16 + i)*16 + o] * (float)e * 0.7071067811865476f;
            }
        }
    }
    W[idx] = val;
}

// ---------------------------------------------------------------- W split bf16 hi/lo, chunk-permuted
// Wc[conv][co][k'] with k' = c5*192 + j*16 + ci16  (ci = c5*16 + ci16, k = j*80+ci).
__global__ void build_Wc(const float* __restrict__ W,
                         unsigned short* __restrict__ Wh, unsigned short* __restrict__ Wl)
{
    int idx = threadIdx.x + blockIdx.x * 256;    // over 2*96*960
    if (idx >= 184320) return;
    int conv = idx / 92160, rem = idx % 92160;
    int co = rem / 960, kp = rem % 960;
    int c5 = kp / 192, r2 = kp % 192;
    int j = r2 / 16, ci16 = r2 % 16;
    int k = j * 80 + c5 * 16 + ci16;
    float w = W[conv * 92160 + k * 96 + co];
    unsigned int u = __float_as_uint(w);
    unsigned int hib = (u + 0x7FFFu + ((u >> 16) & 1u)) & 0xFFFF0000u;  // RNE bf16, as f32 bits
    float res = w - __uint_as_float(hib);
    unsigned int v = __float_as_uint(res);
    unsigned int lob = (v + 0x7FFFu + ((v >> 16) & 1u)) >> 16;
    Wh[idx] = (unsigned short)(hib >> 16);
    Wl[idx] = (unsigned short)lob;
}

// ---------------------------------------------------------------- fused conv (stage A + B)
__device__ __forceinline__ void split8(float4 a, float4 b, bf16x8& hi, bf16x8& lo) {
    float av[8] = {a.x, a.y, a.z, a.w, b.x, b.y, b.z, b.w};
    #pragma unroll
    for (int e = 0; e < 8; e++) {
        unsigned int u = __float_as_uint(av[e]);
        hi[e] = (short)(u >> 16);
        float res = av[e] - __uint_as_float(u & 0xFFFF0000u);
        lo[e] = (short)(__float_as_uint(res) >> 16);
    }
}

__global__ __launch_bounds__(1024, 4) void fused_conv(
    const float* __restrict__ xin, const unsigned short* __restrict__ Wh,
    const unsigned short* __restrict__ Wl, const float* __restrict__ tap,
    float* __restrict__ xout)
{
    // smem: [0,12288)  halo xs: 4 sl x 768 pos x 4 ci        (49.2 KB)
    //       [12288,37376) zc[128][196]  (196%32=4: 2-way write alias = free)  (100.4 KB)
    // epilogue reuses [0,12544) as y[128][98]
    __shared__ float smem[37376];
    int tid = threadIdx.x;
    // stage-A decode: voxel vl (128), ci-pair cg (8, 2 ci each)
    int vl = tid & 127, cg = tid >> 7;
    int dl = vl >> 5, hl = (vl >> 3) & 3, wl = vl & 7;
    // stage-B decode: wave w16 -> row-tile rt (16 voxels), co-half nh (48 cols)
    int w16 = tid >> 6, l = tid & 63;
    int lr = l & 15, lk = l >> 4;
    int rt = w16 >> 1, nh = w16 & 1;
    int bid = blockIdx.x;
    int dt = (bid >> 5) << 2;
    int h0 = ((bid >> 2) & 7) << 2;
    int w0 = (bid & 3) << 3;

    // ---- halo slots (chunk-invariant): 3072 float4 / 1024 thr = 3 each
    int gof[3], lof[3];
    #pragma unroll
    for (int q = 0; q < 3; q++) {
        int i = tid + q * 1024;
        int sl = i / 768, rr = i - sl * 768;
        int dd = rr / 96, rm = rr - dd * 96;
        int hh = rm / 12, ww = rm - hh * 12;
        int gd = dt + dd - 2, gh = h0 + hh - 2, gw = w0 + ww - 2;
        gof[q] = (gd >= 0 && gd < 32 && gh >= 0 && gh < 32 && gw >= 0 && gw < 32)
               ? (((gd << 5) + gh) * 32 + gw) * 80 + sl * 4 : -1;
        lof[q] = sl * 3072 + rr * 4;
    }

    // ---- prologue: load chunk 0 halo
    {
        float4 pf[3];
        #pragma unroll
        for (int q = 0; q < 3; q++)
            pf[q] = (gof[q] >= 0) ? *reinterpret_cast<const float4*>(xin + gof[q])
                                  : make_float4(0.f, 0.f, 0.f, 0.f);
        #pragma unroll
        for (int q = 0; q < 3; q++)
            *reinterpret_cast<float4*>(smem + lof[q]) = pf[q];
    }
    __syncthreads();

    const f32x4 fzero = {0.f, 0.f, 0.f, 0.f};
    f32x4 acc[3];
    #pragma unroll
    for (int nt = 0; nt < 3; nt++) acc[nt] = fzero;

    const float* xp = smem + (cg >> 1) * 3072
                    + (((dl + 2) * 8 + hl + 2) * 12 + (wl + 2)) * 4 + (cg & 1) * 2;
    float* zp = smem + 12288 + vl * 196 + cg * 2;
    const float* ap0 = smem + 12288 + (rt * 16 + lr) * 196 + lk * 8;

    for (int c5 = 0; c5 < 5; c5++) {
        // -- issue prefetch for next chunk (hidden under stage-A VALU)
        float4 pf[3];
        if (c5 < 4) {
            int chof = (c5 + 1) * 16;
            #pragma unroll
            for (int q = 0; q < 3; q++)
                pf[q] = (gof[q] >= 0) ? *reinterpret_cast<const float4*>(xin + gof[q] + chof)
                                      : make_float4(0.f, 0.f, 0.f, 0.f);
        }
        // -- stage A: tap-pair conv for (voxel vl, ci-pair cg) -> zc
        {
            float az[12][2];
            #pragma unroll
            for (int j = 0; j < 12; j++) { az[j][0] = 0.f; az[j][1] = 0.f; }
            {   // center
                const float* rec = tap + 640;
                float2 xc = *reinterpret_cast<const float2*>(xp);
                #pragma unroll
                for (int r = 0; r < 3; r++) {
                    float R = rec[4 + r];
                    az[r*4][0] += R * xc.x; az[r*4][1] += R * xc.y;
                }
            }
            for (int p = 0; p < 40; p++) {
                const float* rec = tap + p * 16;
                int op = __float_as_int(rec[0]) * 4, om = __float_as_int(rec[1]) * 4;
                float2 xa = *reinterpret_cast<const float2*>(xp + op);
                float2 xb = *reinterpret_cast<const float2*>(xp + om);
                float s0 = xa.x + xb.x, s1 = xa.y + xb.y;
                float d0 = xa.x - xb.x, d1 = xa.y - xb.y;
                #pragma unroll
                for (int r = 0; r < 3; r++) {
                    float R = rec[4 + r];
                    az[r*4][0] += R * s0; az[r*4][1] += R * s1;
                    #pragma unroll
                    for (int m = 0; m < 3; m++) {
                        float RY = rec[7 + r*3 + m];
                        az[r*4 + m + 1][0] += RY * d0;
                        az[r*4 + m + 1][1] += RY * d1;
                    }
                }
            }
            #pragma unroll
            for (int j = 0; j < 12; j++)
                *reinterpret_cast<float2*>(zp + j * 16) = make_float2(az[j][0], az[j][1]);
        }
        __syncthreads();                 // zc ready; xs reads done
        // -- write prefetched halo into xs (overlaps MFMA below)
        if (c5 < 4) {
            #pragma unroll
            for (int q = 0; q < 3; q++)
                *reinterpret_cast<float4*>(smem + lof[q]) = pf[q];
        }
        // -- stage B: wave (rt, nh): rows rt*16..+15, cols nh*48 + nt*16
        #pragma unroll
        for (int ks = 0; ks < 6; ks++) {
            const unsigned short* bb = Wh + (nh * 48 + lr) * 960 + c5 * 192 + ks * 32 + lk * 8;
            const unsigned short* bbl = Wl + (nh * 48 + lr) * 960 + c5 * 192 + ks * 32 + lk * 8;
            bf16x8 bh[3], bl[3];
            #pragma unroll
            for (int nt = 0; nt < 3; nt++) {
                bh[nt] = *reinterpret_cast<const bf16x8*>(bb  + nt * 15360);
                bl[nt] = *reinterpret_cast<const bf16x8*>(bbl + nt * 15360);
            }
            const float* ap = ap0 + ks * 32;
            bf16x8 ah, al;
            split8(*reinterpret_cast<const float4*>(ap),
                   *reinterpret_cast<const float4*>(ap + 4), ah, al);
            #pragma unroll
            for (int nt = 0; nt < 3; nt++) {
                acc[nt] = __builtin_amdgcn_mfma_f32_16x16x32_bf16(ah, bh[nt], acc[nt], 0, 0, 0);
                acc[nt] = __builtin_amdgcn_mfma_f32_16x16x32_bf16(al, bh[nt], acc[nt], 0, 0, 0);
                acc[nt] = __builtin_amdgcn_mfma_f32_16x16x32_bf16(ah, bl[nt], acc[nt], 0, 0, 0);
            }
        }
        __syncthreads();                 // zc reads done; xs writes visible
    }

    // ---- epilogue: y -> gate -> store (reuse smem as y[128][98])
    float* y = smem;
    // C/D layout: col = lane&15, row = (lane>>4)*4 + reg
    #pragma unroll
    for (int nt = 0; nt < 3; nt++)
        #pragma unroll
        for (int r = 0; r < 4; r++)
            y[(rt * 16 + lk * 4 + r) * 98 + nh * 48 + nt * 16 + lr] = acc[nt][r];
    __syncthreads();
    #pragma unroll
    for (int it = 0; it < 10; it++) {
        int idx = tid + it * 1024;
        int vr = idx / 80, c = idx - vr * 80;
        int gd = dt + (vr >> 5), gh = h0 + ((vr >> 3) & 3), gw = w0 + (vr & 7);
        const float* yr = y + vr * 98;
        float val;
        if (c < 32) val = fmaxf(yr[c], 0.f);
        else {
            int q = c - 32;
            float g = 1.f / (1.f + __expf(-yr[32 + q / 3]));
            val = yr[48 + q] * g;
        }
        xout[(size_t)(((gd << 5) + gh) * 32 + gw) * 80 + c] = val;
    }
}

// ---------------------------------------------------------------- Final head (float4 stores)
__global__ __launch_bounds__(256) void final_k(
    const float* __restrict__ x2, const float* __restrict__ wls,
    const float* __restrict__ wlv, const float* __restrict__ wpos,
    float* __restrict__ out)
{
    __shared__ float xv[16 * 81];
    __shared__ float coeff[16 * 161];
    __shared__ float s_wls[512];
    __shared__ float s_wlv[768];
    int t = threadIdx.x;
    int bid = blockIdx.x;
    int cw0 = (bid & 1) * 16;
    int ch  = (bid >> 1) & 31;
    int cd  = bid >> 6;
    float wp = wpos[0];
    {
        int base = ((cd * 32 + ch) * 32 + cw0) * 80;
        #pragma unroll
        for (int i = t; i < 1280; i += 256) {
            int vi = i / 80, c = i % 80;
            xv[vi * 81 + c] = x2[base + i];
        }
        for (int i = t; i < 512; i += 256) s_wls[i] = wls[i];
        for (int i = t; i < 768; i += 256) s_wlv[i] = wlv[i];
    }
    __syncthreads();
    {
        int vi = t >> 4, j = t & 15;
        const float* xp = xv + vi * 81;
        float* cf = coeff + vi * 161;
        #pragma unroll
        for (int l = 0; l < 10; l++) {
            int q = l * 16 + j;
            float sum = 0.f;
            if (q < 96) {
                int o = q / 3, m = q % 3;
                #pragma unroll
                for (int c = 0; c < 16; c++) sum += xp[32 + c * 3 + m] * s_wls[c * 32 + o];
            } else if (q < 112) {
                int o = q - 96;
                #pragma unroll
                for (int c = 0; c < 32; c++) sum += xp[c] * s_wlv[c * 16 + o];
            } else {
                int q2 = q - 112; int o = q2 / 3, m = q2 % 3;
                #pragma unroll
                for (int c = 0; c < 16; c++) sum += xp[32 + c * 3 + m] * s_wlv[(32 + c) * 16 + o];
            }
            cf[q] = sum;
        }
    }
    __syncthreads();
    const float scale = 0.14433756729740643f;
    #pragma unroll
    for (int f01 = 0; f01 < 4; f01++) {
        int fd = 2 * cd + (f01 >> 1), fh = 2 * ch + (f01 & 1);
        float p0 = wp * (float)(cd + (f01 >> 1) - 16);
        float p1 = wp * (float)(ch + (f01 & 1) - 16);
        size_t obase = (size_t)((fd * 64 + fh) * 64 + cw0 * 2) * 80;
        #pragma unroll
        for (int it = 0; it < 3; it++) {
            int idx4 = it * 256 + t;
            if (idx4 < 640) {
                int base = idx4 * 4;
                int fwl = base / 80, c0 = base - fwl * 80;
                int vi = fwl >> 1;
                float p2 = wp * (float)(cw0 + vi + (fwl & 1) - 16);
                const float* cf = coeff + vi * 161;
                float vv[4];
                if (c0 < 32) {
                    #pragma unroll
                    for (int e = 0; e < 4; e++) {
                        int c = c0 + e;
                        vv[e] = cf[c * 3] * p0 + cf[c * 3 + 1] * p1 + cf[c * 3 + 2] * p2;
                    }
                } else {
                    #pragma unroll
                    for (int e = 0; e < 4; e++) {
                        int q = c0 - 32 + e, o = q / 3, m = q - o * 3;
                        float A = cf[96 + o];
                        const float* w2 = cf + 112 + o * 3;
                        float pm, crm;
                        if (m == 0)      { pm = p0; crm = w2[1] * p2 - w2[2] * p1; }
                        else if (m == 1) { pm = p1; crm = w2[2] * p0 - w2[0] * p2; }
                        else             { pm = p2; crm = w2[0] * p1 - w2[1] * p0; }
                        vv[e] = A * pm + crm * 0.7071067811865476f;
                    }
                }
                *reinterpret_cast<float4*>(out + obase + base) =
                    make_float4(vv[0]*scale, vv[1]*scale, vv[2]*scale, vv[3]*scale);
            }
        }
    }
}

// ----------------------------------------------------------------
extern "C" void kernel_launch(void* const* d_in, const int* in_sizes, int n_in,
                              void* d_out, int out_size, void* d_ws, size_t ws_size,
                              hipStream_t stream)
{
    const float* x    = (const float*)d_in[0];
    const float* wpos = (const float*)d_in[11];
    const float* wls  = (const float*)d_in[12];
    const float* wlv  = (const float*)d_in[13];
    float* out = (float*)d_out;
    float* ws  = (float*)d_ws;

    float* tap = ws;                        // 656 floats -> pad 1024
    float* W   = ws + 1024;                 // 184320 fp32
    unsigned short* Wh = (unsigned short*)(ws + 1024 + 184320);   // 184320 ushorts
    unsigned short* Wl = Wh + 184320;                              // 184320 ushorts
    float* x1  = ws + 1024 + 184320 + 184320;   // (2 ushort arrays = 184320 floats)
    float* x2  = x1 + 2621440;

    build_tap<<<1, 128, 0, stream>>>(tap);
    build_W<<<720, 256, 0, stream>>>(W,
        (const float*)d_in[1], (const float*)d_in[2], (const float*)d_in[3],
        (const float*)d_in[4], (const float*)d_in[5],
        (const float*)d_in[6], (const float*)d_in[7], (const float*)d_in[8],
        (const float*)d_in[9], (const float*)d_in[10]);
    build_Wc<<<720, 256, 0, stream>>>(W, Wh, Wl);

    fused_conv<<<256, 1024, 0, stream>>>(x,  Wh,         Wl,         tap, x1);
    fused_conv<<<256, 1024, 0, stream>>>(x1, Wh + 92160, Wl + 92160, tap, x2);
    final_k<<<2048, 256, 0, stream>>>(x2, wls, wlv, wpos, out);
}

// Round 5
// 370.972 us; speedup vs baseline: 1.6231x; 1.1088x over previous
//
#include <hip/hip_runtime.h>
#include <math.h>

// x: [1,32,32,32,80] fp32 (80 = 32 scalars + 16 vec*3)
// conv: low-rank kernel basis 12 = 3 radial * {1, Yd, Yh, Yw}
// FUSED conv, 16 waves, PHASE-MERGED pipeline per 128-voxel tile (4x4x8):
//   5 chunks of 16 ci; per chunk two regions:
//     P1: waves 0-7  stage-A(vox 0-63)  ||  waves 8-15 stage-B(rows 64-127, chunk c-1)
//     P2: waves 0-7  stage-B(rows 0-63, chunk c)  ||  waves 8-15 stage-A(vox 64-127)
//     P3: halo write (chunk c+1)
//   z stored PRE-SPLIT bf16 hi/lo in LDS (B does ds_read_b128 -> MFMA directly).
// out: [1,64,64,64,80] fp32

typedef __attribute__((ext_vector_type(8))) short bf16x8;
typedef __attribute__((ext_vector_type(4))) float f32x4;

__device__ __forceinline__ int eps3(int a, int m, int b) {
    if (a == b || a == m || m == b) return 0;
    return ((a==0&&m==1&&b==2)||(a==1&&m==2&&b==0)||(a==2&&m==0&&b==1)) ? 1 : -1;
}

// ---------------------------------------------------------------- tap-pair table
// offsets stored in FLOAT units of the halo layout: pos = d*96+h*12+w, stride 18 fl
__global__ void build_tap(float* __restrict__ tap) {
    int t = threadIdx.x;
    if (t >= 125) return;
    int td = t / 25 - 2, th = (t / 5) % 5 - 2, tw = t % 5 - 2;
    int n2 = td*td + th*th + tw*tw;
    if (t == 62) {                       // center tap
        float* rec = tap + 40 * 16;
        rec[0] = __int_as_float(0); rec[1] = __int_as_float(0);
        for (int r = 0; r < 3; r++) {
            float tt = (0.f - 1.25f * (float)r) * 0.8f;
            rec[4 + r] = expf(-tt * tt);
        }
        return;
    }
    bool active = n2 <= 6;
    bool pos = (td > 0) || (td == 0 && th > 0) || (td == 0 && th == 0 && tw > 0);
    if (!(active && pos)) return;
    int idx = 0;                          // compact index among positive reps
    for (int q = 0; q < t; q++) {
        int qd = q / 25 - 2, qh = (q / 5) % 5 - 2, qw = q % 5 - 2;
        int m2 = qd*qd + qh*qh + qw*qw;
        bool p = (qd > 0) || (qd == 0 && qh > 0) || (qd == 0 && qh == 0 && qw > 0);
        if (m2 <= 6 && p) idx++;
    }
    float* rec = tap + idx * 16;
    int off = (td * 96 + th * 12 + tw) * 18;
    rec[0] = __int_as_float(off);
    rec[1] = __int_as_float(-off);
    float norm = sqrtf((float)n2);
    float comp[3] = {(float)td, (float)th, (float)tw};
    for (int r = 0; r < 3; r++) {
        float tt = (norm - 1.25f * (float)r) * 0.8f;
        float R = expf(-tt * tt);
        rec[4 + r] = R;
        for (int m = 0; m < 3; m++)
            rec[7 + r*3 + m] = R * 1.7320508075688772f * comp[m] / norm;
    }
}

// ---------------------------------------------------------------- W matrices (fp32 source)
__global__ void build_W(float* __restrict__ W,
    const float* __restrict__ ss1, const float* __restrict__ sv1,
    const float* __restrict__ vs1, const float* __restrict__ vv01, const float* __restrict__ vv11,
    const float* __restrict__ ss2, const float* __restrict__ sv2,
    const float* __restrict__ vs2, const float* __restrict__ vv02, const float* __restrict__ vv12)
{
    int idx = threadIdx.x + blockIdx.x * 256;
    if (idx >= 184320) return;
    int conv = idx / 92160;
    int rem  = idx % 92160;
    int j  = rem / 7680;
    int ci = (rem / 96) % 80;
    int co = rem % 96;
    int r = j >> 2, al = j & 3;
    const float* ss  = conv ? ss2  : ss1;
    const float* sv  = conv ? sv2  : sv1;
    const float* vs  = conv ? vs2  : vs1;
    const float* vv0 = conv ? vv02 : vv01;
    const float* vv1 = conv ? vv12 : vv11;
    float val = 0.f;
    if (ci < 32) {
        if (co < 48) { if (al == 0) val = ss[(r*32 + ci)*48 + co]; }
        else {
            int o = (co - 48) / 3, m = (co - 48) % 3;
            if (al == m + 1) val = sv[(r*32 + ci)*16 + o];
        }
    } else {
        int i = (ci - 32) / 3, a = (ci - 32) % 3;
        if (co < 48) { if (al == a + 1) val = vs[(r*16 + i)*48 + co] * 0.5773502691896258f; }
        else {
            int o = (co - 48) / 3, b = (co - 48) % 3;
            if (al == 0) { if (a == b) val = vv0[(r*16 + i)*16 + o]; }
            else {
                int e = eps3(a, al - 1, b);
                if (e) val = vv1[(r*16 + i)*16 + o] * (float)e * 0.7071067811865476f;
            }
        }
    }
    W[idx] = val;
}

// ---------------------------------------------------------------- W split bf16 hi/lo, chunk-permuted
// Wc[conv][co][k'] with k' = c5*192 + j*16 + ci16  (ci = c5*16 + ci16, k = j*80+ci).
__global__ void build_Wc(const float* __restrict__ W,
                         unsigned short* __restrict__ Wh, unsigned short* __restrict__ Wl)
{
    int idx = threadIdx.x + blockIdx.x * 256;    // over 2*96*960
    if (idx >= 184320) return;
    int conv = idx / 92160, rem = idx % 92160;
    int co = rem / 960, kp = rem % 960;
    int c5 = kp / 192, r2 = kp % 192;
    int j = r2 / 16, ci16 = r2 % 16;
    int k = j * 80 + c5 * 16 + ci16;
    float w = W[conv * 92160 + k * 96 + co];
    unsigned int u = __float_as_uint(w);
    unsigned int hib = (u + 0x7FFFu + ((u >> 16) & 1u)) & 0xFFFF0000u;  // RNE bf16, as f32 bits
    float res = w - __uint_as_float(hib);
    unsigned int v = __float_as_uint(res);
    unsigned int lob = (v + 0x7FFFu + ((v >> 16) & 1u)) >> 16;
    Wh[idx] = (unsigned short)(hib >> 16);
    Wl[idx] = (unsigned short)lob;
}

// ---------------------------------------------------------------- fused conv
// LDS map (floats): [0,13824) halo[768 pos][18] (16 ci + 2 pad)
//                   [13824,26624) zch[128][200 ushort]  (z hi, XOR-swizzled cols)
//                   [26624,39424) zcl[128][200 ushort]  (z lo)
// epilogue reuses [0,12544) as y[128][98]

__device__ __forceinline__ void stageA(
    const float* __restrict__ smem, unsigned short* __restrict__ zch,
    unsigned short* __restrict__ zcl, const float* __restrict__ tap,
    int vox, int cg)
{
    int pos = ((vox >> 5) + 2) * 96 + ((((vox >> 3) & 3)) + 2) * 12 + (vox & 7) + 2;
    const float* xp = smem + pos * 18 + 2 * cg;
    float az[12][2];
    #pragma unroll
    for (int j = 0; j < 12; j++) { az[j][0] = 0.f; az[j][1] = 0.f; }
    {   // center
        const float* rec = tap + 640;
        float2 xc = *reinterpret_cast<const float2*>(xp);
        #pragma unroll
        for (int r = 0; r < 3; r++) {
            float R = rec[4 + r];
            az[r*4][0] += R * xc.x; az[r*4][1] += R * xc.y;
        }
    }
    for (int p = 0; p < 40; p++) {
        const float* rec = tap + p * 16;
        int op = __float_as_int(rec[0]), om = __float_as_int(rec[1]);
        float2 xa = *reinterpret_cast<const float2*>(xp + op);
        float2 xb = *reinterpret_cast<const float2*>(xp + om);
        float s0 = xa.x + xb.x, s1 = xa.y + xb.y;
        float d0 = xa.x - xb.x, d1 = xa.y - xb.y;
        #pragma unroll
        for (int r = 0; r < 3; r++) {
            float R = rec[4 + r];
            az[r*4][0] += R * s0; az[r*4][1] += R * s1;
            #pragma unroll
            for (int m = 0; m < 3; m++) {
                float RY = rec[7 + r*3 + m];
                az[r*4 + m + 1][0] += RY * d0;
                az[r*4 + m + 1][1] += RY * d1;
            }
        }
    }
    // split to bf16 hi/lo, pack ci-pair, swizzled write
    int swz = (vox >> 3) & 3;
    int cg3 = cg & 3;
    #pragma unroll
    for (int j = 0; j < 12; j++) {
        unsigned int hw = 0, lw = 0;
        #pragma unroll
        for (int e = 0; e < 2; e++) {
            float a = az[j][e];
            unsigned int u = __float_as_uint(a);
            unsigned int hi = u >> 16;
            float res = a - __uint_as_float(u & 0xFFFF0000u);
            unsigned int lo2 = __float_as_uint(res) >> 16;
            hw |= hi << (16 * e);
            lw |= lo2 << (16 * e);
        }
        int k = j * 16 + 2 * cg;
        int g = k >> 3;                       // 8-k group
        int blk = g >> 2, sub = (g & 3) ^ swz;
        int offu = vox * 200 + blk * 32 + sub * 8 + 2 * cg3;   // ushort offset (uint-aligned)
        *reinterpret_cast<unsigned int*>(zch + offu) = hw;
        *reinterpret_cast<unsigned int*>(zcl + offu) = lw;
    }
}

__device__ __forceinline__ void stageB(
    const unsigned short* __restrict__ zch, const unsigned short* __restrict__ zcl,
    const unsigned short* __restrict__ Wh, const unsigned short* __restrict__ Wl,
    int c, int brow, int bnh, int lr, int lk, f32x4* acc)
{
    int swzB = (brow >> 3) & 3;
    const unsigned short* zh = zch + brow * 200;
    const unsigned short* zl = zcl + brow * 200;
    const unsigned short* wb  = Wh + (bnh * 48 + lr) * 960 + c * 192 + lk * 8;
    const unsigned short* wbl = Wl + (bnh * 48 + lr) * 960 + c * 192 + lk * 8;
    int sub = (lk ^ swzB) * 8;
    #pragma unroll
    for (int ks = 0; ks < 6; ks++) {
        bf16x8 bh[3], bl[3];
        #pragma unroll
        for (int nt = 0; nt < 3; nt++) {
            bh[nt] = *reinterpret_cast<const bf16x8*>(wb  + nt * 15360 + ks * 32);
            bl[nt] = *reinterpret_cast<const bf16x8*>(wbl + nt * 15360 + ks * 32);
        }
        int ao = ks * 32 + sub;
        bf16x8 ah = *reinterpret_cast<const bf16x8*>(zh + ao);
        bf16x8 al = *reinterpret_cast<const bf16x8*>(zl + ao);
        #pragma unroll
        for (int nt = 0; nt < 3; nt++) {
            acc[nt] = __builtin_amdgcn_mfma_f32_16x16x32_bf16(ah, bh[nt], acc[nt], 0, 0, 0);
            acc[nt] = __builtin_amdgcn_mfma_f32_16x16x32_bf16(al, bh[nt], acc[nt], 0, 0, 0);
            acc[nt] = __builtin_amdgcn_mfma_f32_16x16x32_bf16(ah, bl[nt], acc[nt], 0, 0, 0);
        }
    }
}

__global__ __attribute__((amdgpu_flat_work_group_size(1024, 1024), amdgpu_waves_per_eu(4)))
void fused_conv(
    const float* __restrict__ xin, const unsigned short* __restrict__ Wh,
    const unsigned short* __restrict__ Wl, const float* __restrict__ tap,
    float* __restrict__ xout)
{
    __shared__ float smem[39424];
    unsigned short* zch = reinterpret_cast<unsigned short*>(smem + 13824);
    unsigned short* zcl = reinterpret_cast<unsigned short*>(smem + 26624);
    int tid = threadIdx.x;
    int wv = tid >> 6, l = tid & 63;
    int lr = l & 15, lk = l >> 4;
    bool logrp = wv < 8;
    int cg = wv & 7;
    int brt = (wv & 7) >> 1, bnh = wv & 1;
    int rowbase = (logrp ? 0 : 64) + brt * 16;
    int brow = rowbase + lr;
    int bid = blockIdx.x;
    int dt = (bid >> 5) << 2;
    int h0 = ((bid >> 2) & 7) << 2;
    int w0 = (bid & 3) << 3;

    // ---- halo slots (chunk-invariant): 3072 float4 / 1024 thr = 3 each
    int gof[3], lof[3];
    #pragma unroll
    for (int q = 0; q < 3; q++) {
        int i = tid + q * 1024;
        int sl = i / 768, rr = i - sl * 768;
        int dd = rr / 96, rm = rr - dd * 96;
        int hh = rm / 12, ww = rm - hh * 12;
        int gd = dt + dd - 2, gh = h0 + hh - 2, gw = w0 + ww - 2;
        gof[q] = (gd >= 0 && gd < 32 && gh >= 0 && gh < 32 && gw >= 0 && gw < 32)
               ? (((gd << 5) + gh) * 32 + gw) * 80 + sl * 4 : -1;
        lof[q] = rr * 18 + sl * 4;
    }

    // ---- prologue: halo chunk 0
    {
        float4 pf[3];
        #pragma unroll
        for (int q = 0; q < 3; q++)
            pf[q] = (gof[q] >= 0) ? *reinterpret_cast<const float4*>(xin + gof[q])
                                  : make_float4(0.f, 0.f, 0.f, 0.f);
        #pragma unroll
        for (int q = 0; q < 3; q++) {
            *reinterpret_cast<float2*>(smem + lof[q])     = make_float2(pf[q].x, pf[q].y);
            *reinterpret_cast<float2*>(smem + lof[q] + 2) = make_float2(pf[q].z, pf[q].w);
        }
    }
    __syncthreads();

    const f32x4 fzero = {0.f, 0.f, 0.f, 0.f};
    f32x4 acc[3];
    #pragma unroll
    for (int nt = 0; nt < 3; nt++) acc[nt] = fzero;

    for (int c = 0; c < 5; c++) {
        // issue prefetch for chunk c+1 (lands in P3)
        float4 pf[3];
        if (c < 4) {
            int chof = (c + 1) * 16;
            #pragma unroll
            for (int q = 0; q < 3; q++)
                pf[q] = (gof[q] >= 0) ? *reinterpret_cast<const float4*>(xin + gof[q] + chof)
                                      : make_float4(0.f, 0.f, 0.f, 0.f);
        }
        // ---- P1: lo-waves A(vox 0-63, c)  ||  hi-waves B(rows 64-127, c-1)
        if (logrp)      stageA(smem, zch, zcl, tap, l, cg);
        else if (c > 0) stageB(zch, zcl, Wh, Wl, c - 1, brow, bnh, lr, lk, acc);
        __syncthreads();
        // ---- P2: lo-waves B(rows 0-63, c)  ||  hi-waves A(vox 64-127, c)
        if (logrp) stageB(zch, zcl, Wh, Wl, c, brow, bnh, lr, lk, acc);
        else       stageA(smem, zch, zcl, tap, 64 + l, cg);
        __syncthreads();
        // ---- P3: write halo chunk c+1
        if (c < 4) {
            #pragma unroll
            for (int q = 0; q < 3; q++) {
                *reinterpret_cast<float2*>(smem + lof[q])     = make_float2(pf[q].x, pf[q].y);
                *reinterpret_cast<float2*>(smem + lof[q] + 2) = make_float2(pf[q].z, pf[q].w);
            }
        }
        __syncthreads();
    }
    // ---- tail: hi-waves B(rows 64-127, chunk 4)
    if (!logrp) stageB(zch, zcl, Wh, Wl, 4, brow, bnh, lr, lk, acc);
    __syncthreads();

    // ---- epilogue: y -> gate -> store (reuse smem as y[128][98])
    float* y = smem;
    // C/D layout: col = lane&15, row = (lane>>4)*4 + reg
    #pragma unroll
    for (int nt = 0; nt < 3; nt++)
        #pragma unroll
        for (int r = 0; r < 4; r++)
            y[(rowbase + lk * 4 + r) * 98 + bnh * 48 + nt * 16 + lr] = acc[nt][r];
    __syncthreads();
    #pragma unroll
    for (int it = 0; it < 10; it++) {
        int idx = tid + it * 1024;
        int vr = idx / 80, c = idx - vr * 80;
        int gd = dt + (vr >> 5), gh = h0 + ((vr >> 3) & 3), gw = w0 + (vr & 7);
        const float* yr = y + vr * 98;
        float val;
        if (c < 32) val = fmaxf(yr[c], 0.f);
        else {
            int q = c - 32;
            float g = 1.f / (1.f + __expf(-yr[32 + q / 3]));
            val = yr[48 + q] * g;
        }
        xout[(size_t)(((gd << 5) + gh) * 32 + gw) * 80 + c] = val;
    }
}

// ---------------------------------------------------------------- Final head (float4 stores)
__global__ __launch_bounds__(256) void final_k(
    const float* __restrict__ x2, const float* __restrict__ wls,
    const float* __restrict__ wlv, const float* __restrict__ wpos,
    float* __restrict__ out)
{
    __shared__ float xv[16 * 81];
    __shared__ float coeff[16 * 161];
    __shared__ float s_wls[512];
    __shared__ float s_wlv[768];
    int t = threadIdx.x;
    int bid = blockIdx.x;
    int cw0 = (bid & 1) * 16;
    int ch  = (bid >> 1) & 31;
    int cd  = bid >> 6;
    float wp = wpos[0];
    {
        int base = ((cd * 32 + ch) * 32 + cw0) * 80;
        #pragma unroll
        for (int i = t; i < 1280; i += 256) {
            int vi = i / 80, c = i % 80;
            xv[vi * 81 + c] = x2[base + i];
        }
        for (int i = t; i < 512; i += 256) s_wls[i] = wls[i];
        for (int i = t; i < 768; i += 256) s_wlv[i] = wlv[i];
    }
    __syncthreads();
    {
        int vi = t >> 4, j = t & 15;
        const float* xp = xv + vi * 81;
        float* cf = coeff + vi * 161;
        #pragma unroll
        for (int l = 0; l < 10; l++) {
            int q = l * 16 + j;
            float sum = 0.f;
            if (q < 96) {
                int o = q / 3, m = q % 3;
                #pragma unroll
                for (int c = 0; c < 16; c++) sum += xp[32 + c * 3 + m] * s_wls[c * 32 + o];
            } else if (q < 112) {
                int o = q - 96;
                #pragma unroll
                for (int c = 0; c < 32; c++) sum += xp[c] * s_wlv[c * 16 + o];
            } else {
                int q2 = q - 112; int o = q2 / 3, m = q2 % 3;
                #pragma unroll
                for (int c = 0; c < 16; c++) sum += xp[32 + c * 3 + m] * s_wlv[(32 + c) * 16 + o];
            }
            cf[q] = sum;
        }
    }
    __syncthreads();
    const float scale = 0.14433756729740643f;
    #pragma unroll
    for (int f01 = 0; f01 < 4; f01++) {
        int fd = 2 * cd + (f01 >> 1), fh = 2 * ch + (f01 & 1);
        float p0 = wp * (float)(cd + (f01 >> 1) - 16);
        float p1 = wp * (float)(ch + (f01 & 1) - 16);
        size_t obase = (size_t)((fd * 64 + fh) * 64 + cw0 * 2) * 80;
        #pragma unroll
        for (int it = 0; it < 3; it++) {
            int idx4 = it * 256 + t;
            if (idx4 < 640) {
                int base = idx4 * 4;
                int fwl = base / 80, c0 = base - fwl * 80;
                int vi = fwl >> 1;
                float p2 = wp * (float)(cw0 + vi + (fwl & 1) - 16);
                const float* cf = coeff + vi * 161;
                float vv[4];
                if (c0 < 32) {
                    #pragma unroll
                    for (int e = 0; e < 4; e++) {
                        int c = c0 + e;
                        vv[e] = cf[c * 3] * p0 + cf[c * 3 + 1] * p1 + cf[c * 3 + 2] * p2;
                    }
                } else {
                    #pragma unroll
                    for (int e = 0; e < 4; e++) {
                        int q = c0 - 32 + e, o = q / 3, m = q - o * 3;
                        float A = cf[96 + o];
                        const float* w2 = cf + 112 + o * 3;
                        float pm, crm;
                        if (m == 0)      { pm = p0; crm = w2[1] * p2 - w2[2] * p1; }
                        else if (m == 1) { pm = p1; crm = w2[2] * p0 - w2[0] * p2; }
                        else             { pm = p2; crm = w2[0] * p1 - w2[1] * p0; }
                        vv[e] = A * pm + crm * 0.7071067811865476f;
                    }
                }
                *reinterpret_cast<float4*>(out + obase + base) =
                    make_float4(vv[0]*scale, vv[1]*scale, vv[2]*scale, vv[3]*scale);
            }
        }
    }
}

// ----------------------------------------------------------------
extern "C" void kernel_launch(void* const* d_in, const int* in_sizes, int n_in,
                              void* d_out, int out_size, void* d_ws, size_t ws_size,
                              hipStream_t stream)
{
    const float* x    = (const float*)d_in[0];
    const float* wpos = (const float*)d_in[11];
    const float* wls  = (const float*)d_in[12];
    const float* wlv  = (const float*)d_in[13];
    float* out = (float*)d_out;
    float* ws  = (float*)d_ws;

    float* tap = ws;                        // 656 floats -> pad 1024
    float* W   = ws + 1024;                 // 184320 fp32
    unsigned short* Wh = (unsigned short*)(ws + 1024 + 184320);   // 184320 ushorts
    unsigned short* Wl = Wh + 184320;                              // 184320 ushorts
    float* x1  = ws + 1024 + 184320 + 184320;   // (2 ushort arrays = 184320 floats)
    float* x2  = x1 + 2621440;

    build_tap<<<1, 128, 0, stream>>>(tap);
    build_W<<<720, 256, 0, stream>>>(W,
        (const float*)d_in[1], (const float*)d_in[2], (const float*)d_in[3],
        (const float*)d_in[4], (const float*)d_in[5],
        (const float*)d_in[6], (const float*)d_in[7], (const float*)d_in[8],
        (const float*)d_in[9], (const float*)d_in[10]);
    build_Wc<<<720, 256, 0, stream>>>(W, Wh, Wl);

    fused_conv<<<256, 1024, 0, stream>>>(x,  Wh,         Wl,         tap, x1);
    fused_conv<<<256, 1024, 0, stream>>>(x1, Wh + 92160, Wl + 92160, tap, x2);
    final_k<<<2048, 256, 0, stream>>>(x2, wls, wlv, wpos, out);
}

// Round 8
// 358.165 us; speedup vs baseline: 1.6812x; 1.0358x over previous
//
#include <hip/hip_runtime.h>
#include <math.h>

// x: [1,32,32,32,80] fp32 (80 = 32 scalars + 16 vec*3)
// conv: low-rank kernel basis 12 = 3 radial * {1, Yd, Yh, Yw}
// FUSED conv, 16 waves, PHASE-MERGED pipeline per 128-voxel tile (4x4x8):
//   5 chunks of 16 ci; per chunk:
//     P1: waves 0-7  stage-A(vox 0-63)  ||  waves 8-15 stage-B(rows 64-127, chunk c-1)
//     P2: waves 0-7  stage-B(rows 0-63, chunk c)  ||  waves 8-15 stage-A(vox 64-127)
//     P3: halo write (chunk c+1)
//   Tap table is CONSTEXPR: ds_read offsets are immediates, R/RY are inline literals.
//   z stored PRE-SPLIT bf16 hi/lo in LDS (B does ds_read_b128 -> MFMA directly).
// out: [1,64,64,64,80] fp32

typedef __attribute__((ext_vector_type(8))) short bf16x8;
typedef __attribute__((ext_vector_type(4))) float f32x4;

__device__ __forceinline__ int eps3(int a, int m, int b) {
    if (a == b || a == m || m == b) return 0;
    return ((a==0&&m==1&&b==2)||(a==1&&m==2&&b==0)||(a==2&&m==0&&b==1)) ? 1 : -1;
}

// ---------------------------------------------------------------- constexpr tap table
struct TapTab {
    int   op[40];        // float-offset (halo layout, stride-18 rows), positive rep
    float R[40][3];
    float RY[40][9];
    float Rc[3];         // center radial
};
constexpr float cexpf_(float x) {            // |rel err| ~3e-6 on [-4,0]
    float y = x * (1.f/16.f);
    float s = 1.f + y*(1.f + y*(0.5f + y*((1.f/6.f) + y*((1.f/24.f) + y*(1.f/120.f)))));
    s *= s; s *= s; s *= s; s *= s;
    return s;
}
constexpr float csqrtf_(float x) {
    float g = x > 1.f ? x : 1.f;
    for (int i = 0; i < 40; i++) g = 0.5f*(g + x/g);
    return g;
}
constexpr TapTab make_taps() {
    TapTab T{};
    int idx = 0;
    for (int t = 0; t < 125; t++) {
        int td = t/25 - 2, th = (t/5)%5 - 2, tw = t%5 - 2;
        int n2 = td*td + th*th + tw*tw;
        if (t == 62) {
            for (int r = 0; r < 3; r++) {
                float tt = (0.f - 1.25f*(float)r) * 0.8f;
                T.Rc[r] = cexpf_(-tt*tt);
            }
            continue;
        }
        bool active = n2 <= 6;
        bool pos = (td>0) || (td==0 && th>0) || (td==0 && th==0 && tw>0);
        if (!(active && pos)) continue;
        T.op[idx] = (td*96 + th*12 + tw) * 18;
        float norm = csqrtf_((float)n2);
        float comp[3] = {(float)td, (float)th, (float)tw};
        for (int r = 0; r < 3; r++) {
            float tt = (norm - 1.25f*(float)r) * 0.8f;
            float R = cexpf_(-tt*tt);
            T.R[idx][r] = R;
            for (int m = 0; m < 3; m++)
                T.RY[idx][r*3+m] = R * 1.7320508075688772f * comp[m] / norm;
        }
        idx++;
    }
    return T;
}
__device__ constexpr TapTab TT = make_taps();

// ---------------------------------------------------------------- W matrices (fp32 source)
__global__ void build_W(float* __restrict__ W,
    const float* __restrict__ ss1, const float* __restrict__ sv1,
    const float* __restrict__ vs1, const float* __restrict__ vv01, const float* __restrict__ vv11,
    const float* __restrict__ ss2, const float* __restrict__ sv2,
    const float* __restrict__ vs2, const float* __restrict__ vv02, const float* __restrict__ vv12)
{
    int idx = threadIdx.x + blockIdx.x * 256;
    if (idx >= 184320) return;
    int conv = idx / 92160;
    int rem  = idx % 92160;
    int j  = rem / 7680;
    int ci = (rem / 96) % 80;
    int co = rem % 96;
    int r = j >> 2, al = j & 3;
    const float* ss  = conv ? ss2  : ss1;
    const float* sv  = conv ? sv2  : sv1;
    const float* vs  = conv ? vs2  : vs1;
    const float* vv0 = conv ? vv02 : vv01;
    const float* vv1 = conv ? vv12 : vv11;
    float val = 0.f;
    if (ci < 32) {
        if (co < 48) { if (al == 0) val = ss[(r*32 + ci)*48 + co]; }
        else {
            int o = (co - 48) / 3, m = (co - 48) % 3;
            if (al == m + 1) val = sv[(r*32 + ci)*16 + o];
        }
    } else {
        int i = (ci - 32) / 3, a = (ci - 32) % 3;
        if (co < 48) { if (al == a + 1) val = vs[(r*16 + i)*48 + co] * 0.5773502691896258f; }
        else {
            int o = (co - 48) / 3, b = (co - 48) % 3;
            if (al == 0) { if (a == b) val = vv0[(r*16 + i)*16 + o]; }
            else {
                int e = eps3(a, al - 1, b);
                if (e) val = vv1[(r*16 + i)*16 + o] * (float)e * 0.7071067811865476f;
            }
        }
    }
    W[idx] = val;
}

// ---------------------------------------------------------------- W split bf16 hi/lo, chunk-permuted
// Wc[conv][co][k'] with k' = c5*192 + j*16 + ci16  (ci = c5*16 + ci16, k = j*80+ci).
__global__ void build_Wc(const float* __restrict__ W,
                         unsigned short* __restrict__ Wh, unsigned short* __restrict__ Wl)
{
    int idx = threadIdx.x + blockIdx.x * 256;    // over 2*96*960
    if (idx >= 184320) return;
    int conv = idx / 92160, rem = idx % 92160;
    int co = rem / 960, kp = rem % 960;
    int c5 = kp / 192, r2 = kp % 192;
    int j = r2 / 16, ci16 = r2 % 16;
    int k = j * 80 + c5 * 16 + ci16;
    float w = W[conv * 92160 + k * 96 + co];
    unsigned int u = __float_as_uint(w);
    unsigned int hib = (u + 0x7FFFu + ((u >> 16) & 1u)) & 0xFFFF0000u;  // RNE bf16, as f32 bits
    float res = w - __uint_as_float(hib);
    unsigned int v = __float_as_uint(res);
    unsigned int lob = (v + 0x7FFFu + ((v >> 16) & 1u)) >> 16;
    Wh[idx] = (unsigned short)(hib >> 16);
    Wl[idx] = (unsigned short)lob;
}

// ---------------------------------------------------------------- fused conv
// LDS map (floats): [0,13824) halo[768 pos][18] (16 ci + 2 pad)
//                   [13824,26624) zch[128][200 ushort]  (z hi, XOR-swizzled cols)
//                   [26624,39424) zcl[128][200 ushort]  (z lo)
// epilogue reuses [0,12544) as y[128][98]

__device__ __forceinline__ void stageA(
    const float* __restrict__ smem, unsigned short* __restrict__ zch,
    unsigned short* __restrict__ zcl, int vox, int cg)
{
    int pos = ((vox >> 5) + 2) * 96 + ((((vox >> 3) & 3)) + 2) * 12 + (vox & 7) + 2;
    // bias base so all +-op immediates are positive (max |op| = 3924 floats)
    const float* xpb = smem + pos * 18 + 2 * cg - 3924;
    float az[12][2];
    #pragma unroll
    for (int j = 0; j < 12; j++) { az[j][0] = 0.f; az[j][1] = 0.f; }
    {   // center
        float2 xc = *reinterpret_cast<const float2*>(xpb + 3924);
        #pragma unroll
        for (int r = 0; r < 3; r++) {
            float R = TT.Rc[r];
            az[r*4][0] += R * xc.x; az[r*4][1] += R * xc.y;
        }
    }
    #pragma unroll
    for (int p = 0; p < 40; p++) {
        float2 xa = *reinterpret_cast<const float2*>(xpb + (3924 + TT.op[p]));
        float2 xb = *reinterpret_cast<const float2*>(xpb + (3924 - TT.op[p]));
        float s0 = xa.x + xb.x, s1 = xa.y + xb.y;
        float d0 = xa.x - xb.x, d1 = xa.y - xb.y;
        #pragma unroll
        for (int r = 0; r < 3; r++) {
            float R = TT.R[p][r];
            az[r*4][0] += R * s0; az[r*4][1] += R * s1;
            #pragma unroll
            for (int m = 0; m < 3; m++) {
                float RY = TT.RY[p][r*3+m];
                az[r*4 + m + 1][0] += RY * d0;
                az[r*4 + m + 1][1] += RY * d1;
            }
        }
    }
    // split to bf16 hi/lo, pack ci-pair, swizzled write
    int swz = (vox >> 3) & 3;
    int cg3 = cg & 3;
    #pragma unroll
    for (int j = 0; j < 12; j++) {
        unsigned int hw = 0, lw = 0;
        #pragma unroll
        for (int e = 0; e < 2; e++) {
            float a = az[j][e];
            unsigned int u = __float_as_uint(a);
            unsigned int hi = u >> 16;
            float res = a - __uint_as_float(u & 0xFFFF0000u);
            unsigned int lo2 = __float_as_uint(res) >> 16;
            hw |= hi << (16 * e);
            lw |= lo2 << (16 * e);
        }
        int k = j * 16 + 2 * cg;
        int g = k >> 3;                       // 8-k group
        int blk = g >> 2, sub = (g & 3) ^ swz;
        int offu = vox * 200 + blk * 32 + sub * 8 + 2 * cg3;   // ushort offset (uint-aligned)
        *reinterpret_cast<unsigned int*>(zch + offu) = hw;
        *reinterpret_cast<unsigned int*>(zcl + offu) = lw;
    }
}

__device__ __forceinline__ void stageB(
    const unsigned short* __restrict__ zch, const unsigned short* __restrict__ zcl,
    const unsigned short* __restrict__ Wh, const unsigned short* __restrict__ Wl,
    int c, int brow, int bnh, int lr, int lk, f32x4* acc)
{
    int swzB = (brow >> 3) & 3;
    const unsigned short* zh = zch + brow * 200;
    const unsigned short* zl = zcl + brow * 200;
    const unsigned short* wb  = Wh + (bnh * 48 + lr) * 960 + c * 192 + lk * 8;
    const unsigned short* wbl = Wl + (bnh * 48 + lr) * 960 + c * 192 + lk * 8;
    int sub = (lk ^ swzB) * 8;
    #pragma unroll
    for (int ks = 0; ks < 6; ks++) {
        bf16x8 bh[3], bl[3];
        #pragma unroll
        for (int nt = 0; nt < 3; nt++) {
            bh[nt] = *reinterpret_cast<const bf16x8*>(wb  + nt * 15360 + ks * 32);
            bl[nt] = *reinterpret_cast<const bf16x8*>(wbl + nt * 15360 + ks * 32);
        }
        int ao = ks * 32 + sub;
        bf16x8 ah = *reinterpret_cast<const bf16x8*>(zh + ao);
        bf16x8 al = *reinterpret_cast<const bf16x8*>(zl + ao);
        #pragma unroll
        for (int nt = 0; nt < 3; nt++) {
            acc[nt] = __builtin_amdgcn_mfma_f32_16x16x32_bf16(ah, bh[nt], acc[nt], 0, 0, 0);
            acc[nt] = __builtin_amdgcn_mfma_f32_16x16x32_bf16(al, bh[nt], acc[nt], 0, 0, 0);
            acc[nt] = __builtin_amdgcn_mfma_f32_16x16x32_bf16(ah, bl[nt], acc[nt], 0, 0, 0);
        }
    }
}

__global__ __attribute__((amdgpu_flat_work_group_size(1024, 1024), amdgpu_waves_per_eu(4)))
void fused_conv(
    const float* __restrict__ xin, const unsigned short* __restrict__ Wh,
    const unsigned short* __restrict__ Wl, float* __restrict__ xout)
{
    __shared__ float smem[39424];
    unsigned short* zch = reinterpret_cast<unsigned short*>(smem + 13824);
    unsigned short* zcl = reinterpret_cast<unsigned short*>(smem + 26624);
    int tid = threadIdx.x;
    int wv = tid >> 6, l = tid & 63;
    int lr = l & 15, lk = l >> 4;
    bool logrp = wv < 8;
    int cg = wv & 7;
    int brt = (wv & 7) >> 1, bnh = wv & 1;
    int rowbase = (logrp ? 0 : 64) + brt * 16;
    int brow = rowbase + lr;
    int bid = blockIdx.x;
    int dt = (bid >> 5) << 2;
    int h0 = ((bid >> 2) & 7) << 2;
    int w0 = (bid & 3) << 3;

    // ---- halo slots (chunk-invariant): 3072 float4 / 1024 thr = 3 each
    int gof[3], lof[3];
    #pragma unroll
    for (int q = 0; q < 3; q++) {
        int i = tid + q * 1024;
        int sl = i / 768, rr = i - sl * 768;
        int dd = rr / 96, rm = rr - dd * 96;
        int hh = rm / 12, ww = rm - hh * 12;
        int gd = dt + dd - 2, gh = h0 + hh - 2, gw = w0 + ww - 2;
        gof[q] = (gd >= 0 && gd < 32 && gh >= 0 && gh < 32 && gw >= 0 && gw < 32)
               ? (((gd << 5) + gh) * 32 + gw) * 80 + sl * 4 : -1;
        lof[q] = rr * 18 + sl * 4;
    }

    // ---- prologue: halo chunk 0
    {
        float4 pf[3];
        #pragma unroll
        for (int q = 0; q < 3; q++)
            pf[q] = (gof[q] >= 0) ? *reinterpret_cast<const float4*>(xin + gof[q])
                                  : make_float4(0.f, 0.f, 0.f, 0.f);
        #pragma unroll
        for (int q = 0; q < 3; q++) {
            *reinterpret_cast<float2*>(smem + lof[q])     = make_float2(pf[q].x, pf[q].y);
            *reinterpret_cast<float2*>(smem + lof[q] + 2) = make_float2(pf[q].z, pf[q].w);
        }
    }
    __syncthreads();

    const f32x4 fzero = {0.f, 0.f, 0.f, 0.f};
    f32x4 acc[3];
    #pragma unroll
    for (int nt = 0; nt < 3; nt++) acc[nt] = fzero;

    for (int c = 0; c < 5; c++) {
        // issue prefetch for chunk c+1 (lands in P3)
        float4 pf[3];
        if (c < 4) {
            int chof = (c + 1) * 16;
            #pragma unroll
            for (int q = 0; q < 3; q++)
                pf[q] = (gof[q] >= 0) ? *reinterpret_cast<const float4*>(xin + gof[q] + chof)
                                      : make_float4(0.f, 0.f, 0.f, 0.f);
        }
        // ---- P1: lo-waves A(vox 0-63, c)  ||  hi-waves B(rows 64-127, c-1)
        if (logrp)      stageA(smem, zch, zcl, l, cg);
        else if (c > 0) stageB(zch, zcl, Wh, Wl, c - 1, brow, bnh, lr, lk, acc);
        __syncthreads();
        // ---- P2: lo-waves B(rows 0-63, c)  ||  hi-waves A(vox 64-127, c)
        if (logrp) stageB(zch, zcl, Wh, Wl, c, brow, bnh, lr, lk, acc);
        else       stageA(smem, zch, zcl, 64 + l, cg);
        __syncthreads();
        // ---- P3: write halo chunk c+1
        if (c < 4) {
            #pragma unroll
            for (int q = 0; q < 3; q++) {
                *reinterpret_cast<float2*>(smem + lof[q])     = make_float2(pf[q].x, pf[q].y);
                *reinterpret_cast<float2*>(smem + lof[q] + 2) = make_float2(pf[q].z, pf[q].w);
            }
        }
        __syncthreads();
    }
    // ---- tail: hi-waves B(rows 64-127, chunk 4)
    if (!logrp) stageB(zch, zcl, Wh, Wl, 4, brow, bnh, lr, lk, acc);
    __syncthreads();

    // ---- epilogue: y -> gate -> store (reuse smem as y[128][98])
    float* y = smem;
    // C/D layout: col = lane&15, row = (lane>>4)*4 + reg
    #pragma unroll
    for (int nt = 0; nt < 3; nt++)
        #pragma unroll
        for (int r = 0; r < 4; r++)
            y[(rowbase + lk * 4 + r) * 98 + bnh * 48 + nt * 16 + lr] = acc[nt][r];
    __syncthreads();
    #pragma unroll
    for (int it = 0; it < 10; it++) {
        int idx = tid + it * 1024;
        int vr = idx / 80, c = idx - vr * 80;
        int gd = dt + (vr >> 5), gh = h0 + ((vr >> 3) & 3), gw = w0 + (vr & 7);
        const float* yr = y + vr * 98;
        float val;
        if (c < 32) val = fmaxf(yr[c], 0.f);
        else {
            int q = c - 32;
            float g = 1.f / (1.f + __expf(-yr[32 + q / 3]));
            val = yr[48 + q] * g;
        }
        xout[(size_t)(((gd << 5) + gh) * 32 + gw) * 80 + c] = val;
    }
}

// ---------------------------------------------------------------- Final head (nontemporal stores)
__global__ __launch_bounds__(256) void final_k(
    const float* __restrict__ x2, const float* __restrict__ wls,
    const float* __restrict__ wlv, const float* __restrict__ wpos,
    float* __restrict__ out)
{
    __shared__ float xv[16 * 81];
    __shared__ float coeff[16 * 161];
    __shared__ float s_wls[512];
    __shared__ float s_wlv[768];
    int t = threadIdx.x;
    int bid = blockIdx.x;
    int cw0 = (bid & 1) * 16;
    int ch  = (bid >> 1) & 31;
    int cd  = bid >> 6;
    float wp = wpos[0];
    {
        int base = ((cd * 32 + ch) * 32 + cw0) * 80;
        #pragma unroll
        for (int i = t; i < 1280; i += 256) {
            int vi = i / 80, c = i % 80;
            xv[vi * 81 + c] = x2[base + i];
        }
        for (int i = t; i < 512; i += 256) s_wls[i] = wls[i];
        for (int i = t; i < 768; i += 256) s_wlv[i] = wlv[i];
    }
    __syncthreads();
    {
        int vi = t >> 4, j = t & 15;
        const float* xp = xv + vi * 81;
        float* cf = coeff + vi * 161;
        #pragma unroll
        for (int l = 0; l < 10; l++) {
            int q = l * 16 + j;
            float sum = 0.f;
            if (q < 96) {
                int o = q / 3, m = q % 3;
                #pragma unroll
                for (int c = 0; c < 16; c++) sum += xp[32 + c * 3 + m] * s_wls[c * 32 + o];
            } else if (q < 112) {
                int o = q - 96;
                #pragma unroll
                for (int c = 0; c < 32; c++) sum += xp[c] * s_wlv[c * 16 + o];
            } else {
                int q2 = q - 112; int o = q2 / 3, m = q2 % 3;
                #pragma unroll
                for (int c = 0; c < 16; c++) sum += xp[32 + c * 3 + m] * s_wlv[(32 + c) * 16 + o];
            }
            cf[q] = sum;
        }
    }
    __syncthreads();
    const float scale = 0.14433756729740643f;
    #pragma unroll
    for (int f01 = 0; f01 < 4; f01++) {
        int fd = 2 * cd + (f01 >> 1), fh = 2 * ch + (f01 & 1);
        float p0 = wp * (float)(cd + (f01 >> 1) - 16);
        float p1 = wp * (float)(ch + (f01 & 1) - 16);
        size_t obase = (size_t)((fd * 64 + fh) * 64 + cw0 * 2) * 80;
        #pragma unroll
        for (int it = 0; it < 3; it++) {
            int idx4 = it * 256 + t;
            if (idx4 < 640) {
                int base = idx4 * 4;
                int fwl = base / 80, c0 = base - fwl * 80;
                int vi = fwl >> 1;
                float p2 = wp * (float)(cw0 + vi + (fwl & 1) - 16);
                const float* cf = coeff + vi * 161;
                float vv[4];
                if (c0 < 32) {
                    #pragma unroll
                    for (int e = 0; e < 4; e++) {
                        int c = c0 + e;
                        vv[e] = cf[c * 3] * p0 + cf[c * 3 + 1] * p1 + cf[c * 3 + 2] * p2;
                    }
                } else {
                    #pragma unroll
                    for (int e = 0; e < 4; e++) {
                        int q = c0 - 32 + e, o = q / 3, m = q - o * 3;
                        float A = cf[96 + o];
                        const float* w2 = cf + 112 + o * 3;
                        float pm, crm;
                        if (m == 0)      { pm = p0; crm = w2[1] * p2 - w2[2] * p1; }
                        else if (m == 1) { pm = p1; crm = w2[2] * p0 - w2[0] * p2; }
                        else             { pm = p2; crm = w2[0] * p1 - w2[1] * p0; }
                        vv[e] = A * pm + crm * 0.7071067811865476f;
                    }
                }
                f32x4 o4 = {vv[0]*scale, vv[1]*scale, vv[2]*scale, vv[3]*scale};
                __builtin_nontemporal_store(o4, reinterpret_cast<f32x4*>(out + obase + base));
            }
        }
    }
}

// ----------------------------------------------------------------
extern "C" void kernel_launch(void* const* d_in, const int* in_sizes, int n_in,
                              void* d_out, int out_size, void* d_ws, size_t ws_size,
                              hipStream_t stream)
{
    const float* x    = (const float*)d_in[0];
    const float* wpos = (const float*)d_in[11];
    const float* wls  = (const float*)d_in[12];
    const float* wlv  = (const float*)d_in[13];
    float* out = (float*)d_out;
    float* ws  = (float*)d_ws;

    float* W   = ws + 1024;                 // 184320 fp32
    unsigned short* Wh = (unsigned short*)(ws + 1024 + 184320);   // 184320 ushorts
    unsigned short* Wl = Wh + 184320;                              // 184320 ushorts
    float* x1  = ws + 1024 + 184320 + 184320;   // (2 ushort arrays = 184320 floats)
    float* x2  = x1 + 2621440;

    build_W<<<720, 256, 0, stream>>>(W,
        (const float*)d_in[1], (const float*)d_in[2], (const float*)d_in[3],
        (const float*)d_in[4], (const float*)d_in[5],
        (const float*)d_in[6], (const float*)d_in[7], (const float*)d_in[8],
        (const float*)d_in[9], (const float*)d_in[10]);
    build_Wc<<<720, 256, 0, stream>>>(W, Wh, Wl);

    fused_conv<<<256, 1024, 0, stream>>>(x,  Wh,         Wl,         x1);
    fused_conv<<<256, 1024, 0, stream>>>(x1, Wh + 92160, Wl + 92160, x2);
    final_k<<<2048, 256, 0, stream>>>(x2, wls, wlv, wpos, out);
}